// Round 9
// baseline (417.039 us; speedup 1.0000x reference)
//
#include <hip/hip_runtime.h>
#include <hip/hip_bf16.h>

#define N_NODES 50000
#define N_EDGES 200000
#define IN_F 128
#define HEADS 4
#define FD 64
#define HF 256
#define NCOLS 1536
#define NT3 (3 * N_NODES)          // 150000 segment rows (t-major)
#define E3  (3 * N_EDGES)          // 600000 slots
#define TROW 320                   // 5*64 bf16 per (node,head)

// ---- ws byte offsets ----
#define OFF_PROJ   0UL
#define OFF_TABS   51200000UL
#define OFF_ATT    179200000UL
#define OFF_RANK   182400000UL
#define OFF_ELIST  184800000UL
#define OFF_CNT    187200000UL
#define OFF_OFFS   187800000UL
#define OFF_BSUM   188400008UL
#define OFF_BSW    188401040UL
#define OFF_CB     188794256UL

typedef __attribute__((ext_vector_type(8))) short short8;
typedef __attribute__((ext_vector_type(4))) float f32x4;

__device__ inline short bf16_of(float x) {
    __hip_bfloat16 h = __float2bfloat16(x);
    return *reinterpret_cast<short*>(&h);
}
__device__ inline unsigned pack2(float lo, float hi) {
    return ((unsigned)(unsigned short)bf16_of(hi) << 16) |
           (unsigned)(unsigned short)bf16_of(lo);
}
__device__ inline short8 pack8(float4 a, float4 b) {
    short8 o;
    o[0] = bf16_of(a.x); o[1] = bf16_of(a.y); o[2] = bf16_of(a.z); o[3] = bf16_of(a.w);
    o[4] = bf16_of(b.x); o[5] = bf16_of(b.y); o[6] = bf16_of(b.z); o[7] = bf16_of(b.w);
    return o;
}
__device__ inline short8 pack8v(f32x4 a, f32x4 b) {
    short8 o;
    o[0] = bf16_of(a.x); o[1] = bf16_of(a.y); o[2] = bf16_of(a.z); o[3] = bf16_of(a.w);
    o[4] = bf16_of(b.x); o[5] = bf16_of(b.y); o[6] = bf16_of(b.z); o[7] = bf16_of(b.w);
    return o;
}
__device__ inline void unpk(uint4 v, float* f) {
    f[0] = __uint_as_float(v.x << 16); f[1] = __uint_as_float(v.x & 0xffff0000u);
    f[2] = __uint_as_float(v.y << 16); f[3] = __uint_as_float(v.y & 0xffff0000u);
    f[4] = __uint_as_float(v.z << 16); f[5] = __uint_as_float(v.z & 0xffff0000u);
    f[6] = __uint_as_float(v.w << 16); f[7] = __uint_as_float(v.w & 0xffff0000u);
}
__device__ inline float score8(uint4 ua, uint4 ub, uint4 uc, const float* w) {
    float fa[8], fb[8], fc[8]; unpk(ua, fa); unpk(ub, fb); unpk(uc, fc);
    float p = 0.f;
#pragma unroll
    for (int j = 0; j < 8; ++j) {
        float x = fa[j] + fb[j] + fc[j];
        x = fmaxf(x, 0.f);
        p = fmaf(x, w[j], p);
    }
    return p;
}

// ---------------------------------------------------------------------------
// K0: compose weights (table_W1 · W_proj_head) -> pre-swizzled B-frags + colbias
// ---------------------------------------------------------------------------
__global__ __launch_bounds__(128) void k_comp(const float* __restrict__ Wp,
                                              const float* __restrict__ attW1,
                                              const float* __restrict__ eW1,
                                              const float* __restrict__ attb1,
                                              const float* __restrict__ eb1,
                                              __hip_bfloat16* __restrict__ Bsw,
                                              float* __restrict__ colbias) {
    const int c = blockIdx.x;
    const int k = threadIdx.x;
    float acc;
    float cb = 0.f;
    if (c < HF) {
        acc = Wp[c * IN_F + k];
    } else {
        const int t = (c - HF) >> 8;
        const int rem = (c - HF) & 255;
        const int h = rem >> 6, g = rem & 63;
        const float* T;
        if (t == 0)      T = attW1 + g * 192;
        else if (t == 1) T = attW1 + g * 192 + 64;
        else if (t == 2) T = attW1 + g * 192 + 128;
        else if (t == 3) T = eW1 + g * 128;
        else             T = eW1 + g * 128 + 64;
        acc = 0.f;
        for (int f = 0; f < 64; ++f)
            acc += T[f] * Wp[(h * 64 + f) * IN_F + k];
        if (t == 0) cb = attb1[g];
        else if (t == 3) cb = eb1[g];
    }
    const int ct = c >> 4, cin = c & 15, kin = k & 31, j = k & 7;
    const int ks = k >> 5;
    const int l = cin + ((kin >> 3) << 4);
    Bsw[((ct * 4 + ks) * 64 + l) * 8 + j] = __float2bfloat16(acc);
    if (k == 0) colbias[c] = cb;
}

// ---------------------------------------------------------------------------
// K1: [50000x128] @ [128x1536] MFMA GEMM -> proj f32 + packed bf16 tables
// tabs layout: ((node*4 + h)*5 + t)*64 + g
// ---------------------------------------------------------------------------
__global__ __launch_bounds__(256) void k_tab(const float* __restrict__ in,
                                             const __hip_bfloat16* __restrict__ BswH,
                                             const float* __restrict__ colbias,
                                             float* __restrict__ proj,
                                             __hip_bfloat16* __restrict__ tabs) {
    const short8* Bsw = reinterpret_cast<const short8*>(BswH);
    const int lane = threadIdx.x & 63;
    const int wv = threadIdx.x >> 6;
    const int r = lane & 15, q = lane >> 4;
    const int row0 = blockIdx.x * 16;

    short8 a[4];
    const float* ip = in + (size_t)(row0 + r) * IN_F + q * 8;
#pragma unroll
    for (int ks = 0; ks < 4; ++ks) {
        f32x4 lo = __builtin_nontemporal_load((const f32x4*)(ip + ks * 32));
        f32x4 hi = __builtin_nontemporal_load((const f32x4*)(ip + ks * 32 + 4));
        a[ks] = pack8v(lo, hi);
    }

    for (int ctl = 0; ctl < 24; ++ctl) {
        const int ct = wv * 24 + ctl;
        const int c = ct * 16 + r;
        const float cb = colbias[c];
        f32x4 acc = {cb, cb, cb, cb};
#pragma unroll
        for (int ks = 0; ks < 4; ++ks)
            acc = __builtin_amdgcn_mfma_f32_16x16x32_bf16(a[ks], Bsw[(ct * 4 + ks) * 64 + lane], acc, 0, 0, 0);
        if (c < HF) {
#pragma unroll
            for (int i = 0; i < 4; ++i)
                proj[(size_t)(row0 + q * 4 + i) * HF + c] = acc[i];
        } else {
            const int t = (c - HF) >> 8;
            const int rem = (c - HF) & 255;
            const int h = rem >> 6, g = rem & 63;
#pragma unroll
            for (int i = 0; i < 4; ++i)
                tabs[(((size_t)(row0 + q * 4 + i) * HEADS + h) * 5 + t) * 64 + g] =
                    __float2bfloat16(acc[i]);
        }
    }
}

// ---------------------------------------------------------------------------
// Sort chain: hist -> scan (3 kernels) -> scatter edge ids
// ---------------------------------------------------------------------------
__global__ __launch_bounds__(256) void k_hist(const int* __restrict__ eidx,
                                              int* __restrict__ cnt,
                                              int* __restrict__ rank) {
    const int g = blockIdx.x * 256 + threadIdx.x;
    if (g < E3) {
        const int node = eidx[g];
        const int t = g / N_EDGES;
        rank[g] = atomicAdd(&cnt[t * N_NODES + node], 1);
    }
}

__global__ __launch_bounds__(256) void k_scan1(const int* __restrict__ cnt,
                                               int* __restrict__ offs,
                                               int* __restrict__ bsums) {
    __shared__ int lds[256];
    const int b = blockIdx.x, t = threadIdx.x;
    const int base = b * 1024 + t * 4;
    int v[4];
#pragma unroll
    for (int c = 0; c < 4; ++c) v[c] = (base + c < NT3) ? cnt[base + c] : 0;
    const int s = v[0] + v[1] + v[2] + v[3];
    lds[t] = s;
    __syncthreads();
    for (int off = 1; off < 256; off <<= 1) {
        int x = (t >= off) ? lds[t - off] : 0;
        __syncthreads();
        lds[t] += x;
        __syncthreads();
    }
    if (t == 255) bsums[b] = lds[255];
    int run = lds[t] - s;
#pragma unroll
    for (int c = 0; c < 4; ++c) {
        if (base + c < NT3) offs[base + c] = run;
        run += v[c];
    }
}

__global__ __launch_bounds__(256) void k_scan2(int* __restrict__ bsums, int nb) {
    __shared__ int lds[256];
    const int t = threadIdx.x;
    const int v = (t < nb) ? bsums[t] : 0;
    lds[t] = v;
    __syncthreads();
    for (int off = 1; off < 256; off <<= 1) {
        int x = (t >= off) ? lds[t - off] : 0;
        __syncthreads();
        lds[t] += x;
        __syncthreads();
    }
    if (t < nb) bsums[t] = lds[t] - v;
}

__global__ __launch_bounds__(256) void k_scan3(int* __restrict__ offs,
                                               const int* __restrict__ bsums) {
    const int i = blockIdx.x * 256 + threadIdx.x;
    if (i < NT3) offs[i] += bsums[i >> 10];
    if (i == NT3) offs[NT3] = E3;
}

__global__ __launch_bounds__(256) void k_scat(const int* __restrict__ eidx,
                                              const int* __restrict__ offs,
                                              const int* __restrict__ rank,
                                              int* __restrict__ elist) {
    const int g = blockIdx.x * 256 + threadIdx.x;
    if (g < E3) {
        const int node = eidx[g];
        const int t = g / N_EDGES;
        const int e = g - t * N_EDGES;
        elist[offs[t * N_NODES + node] + rank[g]] = e;
    }
}

// ---------------------------------------------------------------------------
// K2: attention scores -> attbuf[e][4]. Block = 16 edges x 4 waves (wave=head).
// ---------------------------------------------------------------------------
__global__ __launch_bounds__(256) void k_att(
        const int* __restrict__ eidx,
        const __hip_bfloat16* __restrict__ tabs,
        const float* __restrict__ attW2, const float* __restrict__ attb2,
        float* __restrict__ attbuf) {
    __shared__ float s_lds[HEADS][16];
    const int lane = threadIdx.x & 63;
    const int h = threadIdx.x >> 6;
    const int r = lane & 15, q = lane >> 4;
    const int e0 = blockIdx.x * 16;

    float awlo[8], awhi[8];
    {
        float4 w0 = *(const float4*)(attW2 + q * 8);
        float4 w1 = *(const float4*)(attW2 + q * 8 + 4);
        awlo[0] = w0.x; awlo[1] = w0.y; awlo[2] = w0.z; awlo[3] = w0.w;
        awlo[4] = w1.x; awlo[5] = w1.y; awlo[6] = w1.z; awlo[7] = w1.w;
        float4 w2 = *(const float4*)(attW2 + 32 + q * 8);
        float4 w3 = *(const float4*)(attW2 + 32 + q * 8 + 4);
        awhi[0] = w2.x; awhi[1] = w2.y; awhi[2] = w2.z; awhi[3] = w2.w;
        awhi[4] = w3.x; awhi[5] = w3.y; awhi[6] = w3.z; awhi[7] = w3.w;
    }
    const float ab2s = attb2[0];

    const int ni = eidx[e0 + r];
    const int nj = eidx[N_EDGES + e0 + r];
    const int nk = eidx[2 * N_EDGES + e0 + r];

    // int32 element offsets (max ~64M, fits unsigned)
    const unsigned co = h * TROW + q * 8;
    const unsigned bi = (unsigned)ni * 1280u + co;
    const unsigned bj = (unsigned)nj * 1280u + co;
    const unsigned bk = (unsigned)nk * 1280u + co;

    uint4 a0 = *(const uint4*)(tabs + bi);
    uint4 a1 = *(const uint4*)(tabs + bi + 32);
    uint4 b0 = *(const uint4*)(tabs + bj + 64);
    uint4 b1 = *(const uint4*)(tabs + bj + 96);
    uint4 c0 = *(const uint4*)(tabs + bk + 128);
    uint4 c1 = *(const uint4*)(tabs + bk + 160);

    float p = score8(a0, b0, c0, awlo) + score8(a1, b1, c1, awhi);
    p += __shfl_xor(p, 16);
    p += __shfl_xor(p, 32);
    float sc = p + ab2s;
    sc = fmaxf(sc, 0.2f * sc);
    if (lane < 16) s_lds[h][lane] = sc;
    __syncthreads();
    if (lane < 16) {
        const float s0 = s_lds[0][lane], s1 = s_lds[1][lane];
        const float s2 = s_lds[2][lane], s3 = s_lds[3][lane];
        const float mx = fmaxf(fmaxf(s0, s1), fmaxf(s2, s3));
        const float x0 = __expf(s0 - mx), x1 = __expf(s1 - mx);
        const float x2 = __expf(s2 - mx), x3 = __expf(s3 - mx);
        const float rs = 1.f / (x0 + x1 + x2 + x3);
        const float xh = (h == 0) ? x0 : (h == 1) ? x1 : (h == 2) ? x2 : x3;
        attbuf[(size_t)(e0 + lane) * 4 + h] = xh * rs;
    }
}

// ---------------------------------------------------------------------------
// K3 (fused): segment-sum + W2 GEMM + elu epilogue.
// nt-hints on single-use streams (elist/attbuf/proj/out) so L3 keeps the
// 51 MB v-tables resident; int32 gather addressing.
// ---------------------------------------------------------------------------
__global__ __launch_bounds__(256) void k_seg(const int* __restrict__ eidx,
                                             const int* __restrict__ offs,
                                             const int* __restrict__ elist,
                                             const float* __restrict__ attbuf,
                                             const __hip_bfloat16* __restrict__ tabs,
                                             const float* __restrict__ proj,
                                             const float* __restrict__ eW2,
                                             const float* __restrict__ eb2,
                                             const float* __restrict__ theta,
                                             const float* __restrict__ bias,
                                             float* __restrict__ out) {
    __shared__ __hip_bfloat16 S_lds[16][72];   // padded: stride 144 B
    __shared__ float a_lds[16];
    __shared__ float D_lds[16][68];            // padded: stride 272 B

    const int lane = threadIdx.x & 63;
    const int w = threadIdx.x >> 6;
    const int h = lane >> 4, r = lane & 15;
    const int q = lane >> 4;                   // MFMA quad index (phase 2)
    const int t = blockIdx.y;
    const int n0 = blockIdx.x * 4;
    const int n = n0 + w;
    const int idx = t * N_NODES + n;
    const int p0 = offs[idx], p1 = offs[idx + 1];
    int s0, s1;
    if (t == 0)      { s0 = 1; s1 = 2; }
    else if (t == 1) { s0 = 0; s1 = 2; }
    else             { s0 = 0; s1 = 1; }

    // loop-invariant element offsets within a node row (elements, not bytes)
    const unsigned c1 = (unsigned)(h * TROW + 192 + r * 4);   // v1 (t=3)
    const unsigned c2 = (unsigned)(h * TROW + 256 + r * 4);   // v2 (t=4)

    // ---- phase 1: 4-wide batched segment accumulation ----
    float acc0 = 0.f, acc1 = 0.f, acc2 = 0.f, acc3 = 0.f, alpha = 0.f;
    for (int base = p0; base < p1; base += 4) {
        int ee[4];
#pragma unroll
        for (int c = 0; c < 4; ++c) {
            const int p = base + c;
            ee[c] = __builtin_nontemporal_load(elist + (p < p1 ? p : p1 - 1));
        }
        unsigned xx[4], yy[4];
        float at[4];
#pragma unroll
        for (int c = 0; c < 4; ++c) {
            xx[c] = (unsigned)eidx[s0 * N_EDGES + ee[c]];
            yy[c] = (unsigned)eidx[s1 * N_EDGES + ee[c]];
        }
#pragma unroll
        for (int c = 0; c < 4; ++c)
            at[c] = (base + c < p1)
                ? __builtin_nontemporal_load(attbuf + (unsigned)ee[c] * 4u + h)
                : 0.f;
        uint2 ua[4], ub[4];
#pragma unroll
        for (int c = 0; c < 4; ++c) {
            ua[c] = *(const uint2*)(tabs + (xx[c] * 1280u + c1));
            ub[c] = *(const uint2*)(tabs + (yy[c] * 1280u + c2));
        }
#pragma unroll
        for (int c = 0; c < 4; ++c) {
            float g0 = __uint_as_float(ua[c].x << 16) + __uint_as_float(ub[c].x << 16);
            float g1 = __uint_as_float(ua[c].x & 0xffff0000u) + __uint_as_float(ub[c].x & 0xffff0000u);
            float g2 = __uint_as_float(ua[c].y << 16) + __uint_as_float(ub[c].y << 16);
            float g3 = __uint_as_float(ua[c].y & 0xffff0000u) + __uint_as_float(ub[c].y & 0xffff0000u);
            g0 = fmaxf(g0, 0.2f * g0); g1 = fmaxf(g1, 0.2f * g1);
            g2 = fmaxf(g2, 0.2f * g2); g3 = fmaxf(g3, 0.2f * g3);
            acc0 = fmaf(at[c], g0, acc0); acc1 = fmaf(at[c], g1, acc1);
            acc2 = fmaf(at[c], g2, acc2); acc3 = fmaf(at[c], g3, acc3);
            alpha += at[c];
        }
    }
    const int tr = w * 4 + h;                  // tile row
    uint2 st;
    st.x = pack2(acc0, acc1);
    st.y = pack2(acc2, acc3);
    *(uint2*)&S_lds[tr][r * 4] = st;
    if (r == 0) a_lds[tr] = alpha;
    __syncthreads();

    // ---- phase 2: wave w = output-feature block ct; D[i][f] to LDS ----
    {
        const float* wp0 = eW2 + (w * 16 + r) * FD + q * 8;
        const float* wp1 = eW2 + (w * 16 + r) * FD + 32 + q * 8;
        short8 bfr0 = pack8(*(const float4*)wp0, *(const float4*)(wp0 + 4));
        short8 bfr1 = pack8(*(const float4*)wp1, *(const float4*)(wp1 + 4));
        short8 A0 = *(short8*)&S_lds[r][q * 8];
        short8 A1 = *(short8*)&S_lds[r][32 + q * 8];
        f32x4 acc = {0.f, 0.f, 0.f, 0.f};
        acc = __builtin_amdgcn_mfma_f32_16x16x32_bf16(A0, bfr0, acc, 0, 0, 0);
        acc = __builtin_amdgcn_mfma_f32_16x16x32_bf16(A1, bfr1, acc, 0, 0, 0);
#pragma unroll
        for (int i = 0; i < 4; ++i)
            D_lds[q * 4 + i][w * 16 + r] = acc[i];
    }
    __syncthreads();

    // ---- phase 3: cooperative vectorized epilogue ----
    const int row = threadIdx.x >> 4;          // 0..15 tile row
    const int c4 = threadIdx.x & 15;           // f-chunk of 4
    const int f = c4 * 4;
    const int hh = row & 3;
    const int nn = n0 + (row >> 2);
    const size_t rho = ((size_t)t * N_NODES + nn) * 4 + hh;

    f32x4 Dv = *(f32x4*)&D_lds[row][f];
    f32x4 pj = __builtin_nontemporal_load(
        (const f32x4*)(proj + (size_t)nn * HF + hh * 64 + f));
    f32x4 th = *(const f32x4*)(theta + hh * 64 + f);
    f32x4 bi = *(const f32x4*)(bias + hh * 64 + f);
    f32x4 b2 = *(const f32x4*)(eb2 + f);
    const float al = a_lds[row];
    f32x4 o;
    float v;
    v = th.x * pj.x + Dv.x + al * b2.x + bi.x; o.x = v > 0.f ? v : expm1f(v);
    v = th.y * pj.y + Dv.y + al * b2.y + bi.y; o.y = v > 0.f ? v : expm1f(v);
    v = th.z * pj.z + Dv.z + al * b2.z + bi.z; o.z = v > 0.f ? v : expm1f(v);
    v = th.w * pj.w + Dv.w + al * b2.w + bi.w; o.w = v > 0.f ? v : expm1f(v);
    __builtin_nontemporal_store(o, (f32x4*)(out + rho * 64 + f));
}

// ---------------------------------------------------------------------------
extern "C" void kernel_launch(void* const* d_in, const int* in_sizes, int n_in,
                              void* d_out, int out_size, void* d_ws, size_t ws_size,
                              hipStream_t stream) {
    const float* in_nodes = (const float*)d_in[0];
    const int*   eidx     = (const int*)d_in[1];
    const float* Wp       = (const float*)d_in[2];
    const float* attW1    = (const float*)d_in[3];
    const float* attb1    = (const float*)d_in[4];
    const float* attW2    = (const float*)d_in[5];
    const float* attb2    = (const float*)d_in[6];
    const float* eW1      = (const float*)d_in[7];
    const float* eb1      = (const float*)d_in[8];
    const float* eW2      = (const float*)d_in[9];
    const float* eb2      = (const float*)d_in[10];
    const float* theta    = (const float*)d_in[11];
    const float* bias     = (const float*)d_in[12];

    char* ws = (char*)d_ws;
    float*          proj     = (float*)(ws + OFF_PROJ);
    __hip_bfloat16* tabs     = (__hip_bfloat16*)(ws + OFF_TABS);
    float*          attbuf   = (float*)(ws + OFF_ATT);
    int*            rank     = (int*)(ws + OFF_RANK);
    int*            elist    = (int*)(ws + OFF_ELIST);
    int*            cnt      = (int*)(ws + OFF_CNT);
    int*            offs     = (int*)(ws + OFF_OFFS);
    int*            bsums    = (int*)(ws + OFF_BSUM);
    __hip_bfloat16* Bsw      = (__hip_bfloat16*)(ws + OFF_BSW);
    float*          colbias  = (float*)(ws + OFF_CB);

    float* out = (float*)d_out;

    (void)hipMemsetAsync(cnt, 0, NT3 * sizeof(int), stream);

    k_comp<<<NCOLS, 128, 0, stream>>>(Wp, attW1, eW1, attb1, eb1, Bsw, colbias);
    k_tab<<<N_NODES / 16, 256, 0, stream>>>(in_nodes, Bsw, colbias, proj, tabs);

    k_hist<<<(E3 + 255) / 256, 256, 0, stream>>>(eidx, cnt, rank);
    k_scan1<<<(NT3 + 1023) / 1024, 256, 0, stream>>>(cnt, offs, bsums);
    k_scan2<<<1, 256, 0, stream>>>(bsums, (NT3 + 1023) / 1024);
    k_scan3<<<(NT3 + 256) / 256, 256, 0, stream>>>(offs, bsums);
    k_scat<<<(E3 + 255) / 256, 256, 0, stream>>>(eidx, offs, rank, elist);

    k_att<<<N_EDGES / 16, 256, 0, stream>>>(eidx, tabs, attW2, attb2, attbuf);
    k_seg<<<dim3(N_NODES / 4, 3), 256, 0, stream>>>(eidx, offs, elist, attbuf,
                                                    tabs, proj, eW2, eb2,
                                                    theta, bias, out);
}

// Round 10
// 390.133 us; speedup vs baseline: 1.0690x; 1.0690x over previous
//
#include <hip/hip_runtime.h>
#include <hip/hip_bf16.h>

#define N_NODES 50000
#define N_EDGES 200000
#define IN_F 128
#define HEADS 4
#define FD 64
#define HF 256
#define NCOLS 1536
#define NT3 (3 * N_NODES)          // 150000 segment rows (t-major)
#define E3  (3 * N_EDGES)          // 600000 slots
#define TROW 320                   // 5*64 bf16 per (node,head)

// ---- ws byte offsets ----
#define OFF_PROJ   0UL
#define OFF_TABS   51200000UL
#define OFF_ATT    179200000UL
#define OFF_RANK   182400000UL
#define OFF_ELIST  184800000UL
#define OFF_CNT    187200000UL
#define OFF_OFFS   187800000UL
#define OFF_BSUM   188400008UL
#define OFF_BSW    188401040UL
#define OFF_CB     188794256UL

typedef __attribute__((ext_vector_type(8))) short short8;
typedef __attribute__((ext_vector_type(4))) float f32x4;

__device__ inline short bf16_of(float x) {
    __hip_bfloat16 h = __float2bfloat16(x);
    return *reinterpret_cast<short*>(&h);
}
__device__ inline unsigned pack2(float lo, float hi) {
    return ((unsigned)(unsigned short)bf16_of(hi) << 16) |
           (unsigned)(unsigned short)bf16_of(lo);
}
__device__ inline short8 pack8(float4 a, float4 b) {
    short8 o;
    o[0] = bf16_of(a.x); o[1] = bf16_of(a.y); o[2] = bf16_of(a.z); o[3] = bf16_of(a.w);
    o[4] = bf16_of(b.x); o[5] = bf16_of(b.y); o[6] = bf16_of(b.z); o[7] = bf16_of(b.w);
    return o;
}
__device__ inline void unpk(uint4 v, float* f) {
    f[0] = __uint_as_float(v.x << 16); f[1] = __uint_as_float(v.x & 0xffff0000u);
    f[2] = __uint_as_float(v.y << 16); f[3] = __uint_as_float(v.y & 0xffff0000u);
    f[4] = __uint_as_float(v.z << 16); f[5] = __uint_as_float(v.z & 0xffff0000u);
    f[6] = __uint_as_float(v.w << 16); f[7] = __uint_as_float(v.w & 0xffff0000u);
}
__device__ inline float score8(uint4 ua, uint4 ub, uint4 uc, const float* w) {
    float fa[8], fb[8], fc[8]; unpk(ua, fa); unpk(ub, fb); unpk(uc, fc);
    float p = 0.f;
#pragma unroll
    for (int j = 0; j < 8; ++j) {
        float x = fa[j] + fb[j] + fc[j];
        x = fmaxf(x, 0.f);
        p = fmaf(x, w[j], p);
    }
    return p;
}

// ---------------------------------------------------------------------------
// K0: compose weights (table_W1 · W_proj_head) -> pre-swizzled B-frags + colbias
// ---------------------------------------------------------------------------
__global__ __launch_bounds__(128) void k_comp(const float* __restrict__ Wp,
                                              const float* __restrict__ attW1,
                                              const float* __restrict__ eW1,
                                              const float* __restrict__ attb1,
                                              const float* __restrict__ eb1,
                                              __hip_bfloat16* __restrict__ Bsw,
                                              float* __restrict__ colbias) {
    const int c = blockIdx.x;
    const int k = threadIdx.x;
    float acc;
    float cb = 0.f;
    if (c < HF) {
        acc = Wp[c * IN_F + k];
    } else {
        const int t = (c - HF) >> 8;
        const int rem = (c - HF) & 255;
        const int h = rem >> 6, g = rem & 63;
        const float* T;
        if (t == 0)      T = attW1 + g * 192;
        else if (t == 1) T = attW1 + g * 192 + 64;
        else if (t == 2) T = attW1 + g * 192 + 128;
        else if (t == 3) T = eW1 + g * 128;
        else             T = eW1 + g * 128 + 64;
        acc = 0.f;
        for (int f = 0; f < 64; ++f)
            acc += T[f] * Wp[(h * 64 + f) * IN_F + k];
        if (t == 0) cb = attb1[g];
        else if (t == 3) cb = eb1[g];
    }
    const int ct = c >> 4, cin = c & 15, kin = k & 31, j = k & 7;
    const int ks = k >> 5;
    const int l = cin + ((kin >> 3) << 4);
    Bsw[((ct * 4 + ks) * 64 + l) * 8 + j] = __float2bfloat16(acc);
    if (k == 0) colbias[c] = cb;
}

// ---------------------------------------------------------------------------
// K1: [50000x128] @ [128x1536] MFMA GEMM -> proj f32 + packed bf16 tables
// tabs layout: ((node*4 + h)*5 + t)*64 + g
// ---------------------------------------------------------------------------
__global__ __launch_bounds__(256) void k_tab(const float* __restrict__ in,
                                             const __hip_bfloat16* __restrict__ BswH,
                                             const float* __restrict__ colbias,
                                             float* __restrict__ proj,
                                             __hip_bfloat16* __restrict__ tabs) {
    const short8* Bsw = reinterpret_cast<const short8*>(BswH);
    const int lane = threadIdx.x & 63;
    const int wv = threadIdx.x >> 6;
    const int r = lane & 15, q = lane >> 4;
    const int row0 = blockIdx.x * 16;

    short8 a[4];
    const float* ip = in + (size_t)(row0 + r) * IN_F + q * 8;
#pragma unroll
    for (int ks = 0; ks < 4; ++ks)
        a[ks] = pack8(*(const float4*)(ip + ks * 32), *(const float4*)(ip + ks * 32 + 4));

    for (int ctl = 0; ctl < 24; ++ctl) {
        const int ct = wv * 24 + ctl;
        const int c = ct * 16 + r;
        const float cb = colbias[c];
        f32x4 acc = {cb, cb, cb, cb};
#pragma unroll
        for (int ks = 0; ks < 4; ++ks)
            acc = __builtin_amdgcn_mfma_f32_16x16x32_bf16(a[ks], Bsw[(ct * 4 + ks) * 64 + lane], acc, 0, 0, 0);
        if (c < HF) {
#pragma unroll
            for (int i = 0; i < 4; ++i)
                proj[(size_t)(row0 + q * 4 + i) * HF + c] = acc[i];
        } else {
            const int t = (c - HF) >> 8;
            const int rem = (c - HF) & 255;
            const int h = rem >> 6, g = rem & 63;
#pragma unroll
            for (int i = 0; i < 4; ++i)
                tabs[(((size_t)(row0 + q * 4 + i) * HEADS + h) * 5 + t) * 64 + g] =
                    __float2bfloat16(acc[i]);
        }
    }
}

// ---------------------------------------------------------------------------
// Sort chain: hist -> scan (3 kernels) -> scatter edge ids
// ---------------------------------------------------------------------------
__global__ __launch_bounds__(256) void k_hist(const int* __restrict__ eidx,
                                              int* __restrict__ cnt,
                                              int* __restrict__ rank) {
    const int g = blockIdx.x * 256 + threadIdx.x;
    if (g < E3) {
        const int node = eidx[g];
        const int t = g / N_EDGES;
        rank[g] = atomicAdd(&cnt[t * N_NODES + node], 1);
    }
}

__global__ __launch_bounds__(256) void k_scan1(const int* __restrict__ cnt,
                                               int* __restrict__ offs,
                                               int* __restrict__ bsums) {
    __shared__ int lds[256];
    const int b = blockIdx.x, t = threadIdx.x;
    const int base = b * 1024 + t * 4;
    int v[4];
#pragma unroll
    for (int c = 0; c < 4; ++c) v[c] = (base + c < NT3) ? cnt[base + c] : 0;
    const int s = v[0] + v[1] + v[2] + v[3];
    lds[t] = s;
    __syncthreads();
    for (int off = 1; off < 256; off <<= 1) {
        int x = (t >= off) ? lds[t - off] : 0;
        __syncthreads();
        lds[t] += x;
        __syncthreads();
    }
    if (t == 255) bsums[b] = lds[255];
    int run = lds[t] - s;
#pragma unroll
    for (int c = 0; c < 4; ++c) {
        if (base + c < NT3) offs[base + c] = run;
        run += v[c];
    }
}

__global__ __launch_bounds__(256) void k_scan2(int* __restrict__ bsums, int nb) {
    __shared__ int lds[256];
    const int t = threadIdx.x;
    const int v = (t < nb) ? bsums[t] : 0;
    lds[t] = v;
    __syncthreads();
    for (int off = 1; off < 256; off <<= 1) {
        int x = (t >= off) ? lds[t - off] : 0;
        __syncthreads();
        lds[t] += x;
        __syncthreads();
    }
    if (t < nb) bsums[t] = lds[t] - v;
}

__global__ __launch_bounds__(256) void k_scan3(int* __restrict__ offs,
                                               const int* __restrict__ bsums) {
    const int i = blockIdx.x * 256 + threadIdx.x;
    if (i < NT3) offs[i] += bsums[i >> 10];
    if (i == NT3) offs[NT3] = E3;
}

__global__ __launch_bounds__(256) void k_scat(const int* __restrict__ eidx,
                                              const int* __restrict__ offs,
                                              const int* __restrict__ rank,
                                              int* __restrict__ elist) {
    const int g = blockIdx.x * 256 + threadIdx.x;
    if (g < E3) {
        const int node = eidx[g];
        const int t = g / N_EDGES;
        const int e = g - t * N_EDGES;
        elist[offs[t * N_NODES + node] + rank[g]] = e;
    }
}

// ---------------------------------------------------------------------------
// K2: attention scores -> attbuf[e][4]. Block = 16 edges x 4 waves (wave=head).
// ---------------------------------------------------------------------------
__global__ __launch_bounds__(256) void k_att(
        const int* __restrict__ eidx,
        const __hip_bfloat16* __restrict__ tabs,
        const float* __restrict__ attW2, const float* __restrict__ attb2,
        float* __restrict__ attbuf) {
    __shared__ float s_lds[HEADS][16];
    const int lane = threadIdx.x & 63;
    const int h = threadIdx.x >> 6;
    const int r = lane & 15, q = lane >> 4;
    const int e0 = blockIdx.x * 16;

    float awlo[8], awhi[8];
    {
        float4 w0 = *(const float4*)(attW2 + q * 8);
        float4 w1 = *(const float4*)(attW2 + q * 8 + 4);
        awlo[0] = w0.x; awlo[1] = w0.y; awlo[2] = w0.z; awlo[3] = w0.w;
        awlo[4] = w1.x; awlo[5] = w1.y; awlo[6] = w1.z; awlo[7] = w1.w;
        float4 w2 = *(const float4*)(attW2 + 32 + q * 8);
        float4 w3 = *(const float4*)(attW2 + 32 + q * 8 + 4);
        awhi[0] = w2.x; awhi[1] = w2.y; awhi[2] = w2.z; awhi[3] = w2.w;
        awhi[4] = w3.x; awhi[5] = w3.y; awhi[6] = w3.z; awhi[7] = w3.w;
    }
    const float ab2s = attb2[0];

    const int ni = eidx[e0 + r];
    const int nj = eidx[N_EDGES + e0 + r];
    const int nk = eidx[2 * N_EDGES + e0 + r];

    const size_t bi = ((size_t)ni * HEADS + h) * TROW + q * 8;
    const size_t bj = ((size_t)nj * HEADS + h) * TROW + q * 8;
    const size_t bk = ((size_t)nk * HEADS + h) * TROW + q * 8;

    uint4 a0 = *(const uint4*)(tabs + bi);
    uint4 a1 = *(const uint4*)(tabs + bi + 32);
    uint4 b0 = *(const uint4*)(tabs + bj + 64);
    uint4 b1 = *(const uint4*)(tabs + bj + 96);
    uint4 c0 = *(const uint4*)(tabs + bk + 128);
    uint4 c1 = *(const uint4*)(tabs + bk + 160);

    float p = score8(a0, b0, c0, awlo) + score8(a1, b1, c1, awhi);
    p += __shfl_xor(p, 16);
    p += __shfl_xor(p, 32);
    float sc = p + ab2s;
    sc = fmaxf(sc, 0.2f * sc);
    if (lane < 16) s_lds[h][lane] = sc;
    __syncthreads();
    if (lane < 16) {
        const float s0 = s_lds[0][lane], s1 = s_lds[1][lane];
        const float s2 = s_lds[2][lane], s3 = s_lds[3][lane];
        const float mx = fmaxf(fmaxf(s0, s1), fmaxf(s2, s3));
        const float x0 = __expf(s0 - mx), x1 = __expf(s1 - mx);
        const float x2 = __expf(s2 - mx), x3 = __expf(s3 - mx);
        const float rs = 1.f / (x0 + x1 + x2 + x3);
        const float xh = (h == 0) ? x0 : (h == 1) ? x1 : (h == 2) ? x2 : x3;
        attbuf[(size_t)(e0 + lane) * 4 + h] = xh * rs;
    }
}

// ---------------------------------------------------------------------------
// K3 (fused): segment-sum + W2 GEMM + elu epilogue.
// Phase 1: the block's 4 consecutive segments form ONE contiguous elist range;
// it is split evenly across the 4 waves (destination node recovered from
// wave-uniform compares) -> no max-degree barrier tail. Per-wave partials in
// f32 LDS, reduced, then MFMA + vectorized epilogue as before.
// ---------------------------------------------------------------------------
__global__ __launch_bounds__(256) void k_seg(const int* __restrict__ eidx,
                                             const int* __restrict__ offs,
                                             const int* __restrict__ elist,
                                             const float* __restrict__ attbuf,
                                             const __hip_bfloat16* __restrict__ tabs,
                                             const float* __restrict__ proj,
                                             const float* __restrict__ eW2,
                                             const float* __restrict__ eb2,
                                             const float* __restrict__ theta,
                                             const float* __restrict__ bias,
                                             float* __restrict__ out) {
    __shared__ float part[4][16][68];          // per-wave f32 partials (17 KB)
    __shared__ float apart[4][16];
    __shared__ __hip_bfloat16 S_lds[16][72];   // reduced bf16 A-tile
    __shared__ float a_lds[16];
    __shared__ float D_lds[16][68];

    const int lane = threadIdx.x & 63;
    const int w = threadIdx.x >> 6;
    const int h = lane >> 4, r = lane & 15;
    const int q = lane >> 4;                   // MFMA quad index (phase 2)
    const int t = blockIdx.y;
    const int n0 = blockIdx.x * 4;
    const int idx0 = t * N_NODES + n0;
    const int o0 = offs[idx0], o1 = offs[idx0 + 1], o2 = offs[idx0 + 2];
    const int o3 = offs[idx0 + 3], o4 = offs[idx0 + 4];
    int s0, s1;
    if (t == 0)      { s0 = 1; s1 = 2; }
    else if (t == 1) { s0 = 0; s1 = 2; }
    else             { s0 = 0; s1 = 1; }

    // even split of the block's combined edge range across the 4 waves
    const int T = o4 - o0;
    const int L = (T + 3) >> 2;
    const int wp0 = o0 + w * L;
    const int wp1 = min(wp0 + L, o4);

    // ---- phase 1a: balanced 4-wide batched accumulation ----
    float c00 = 0.f, c01 = 0.f, c02 = 0.f, c03 = 0.f;
    float c10 = 0.f, c11 = 0.f, c12 = 0.f, c13 = 0.f;
    float c20 = 0.f, c21 = 0.f, c22 = 0.f, c23 = 0.f;
    float c30 = 0.f, c31 = 0.f, c32 = 0.f, c33 = 0.f;
    float al0 = 0.f, al1 = 0.f, al2 = 0.f, al3 = 0.f;

    for (int bp = wp0; bp < wp1; bp += 4) {
        int ee[4];
#pragma unroll
        for (int c = 0; c < 4; ++c) {
            const int p = bp + c;
            ee[c] = elist[p < wp1 ? p : wp1 - 1];
        }
        int xx[4], yy[4];
        float at[4];
#pragma unroll
        for (int c = 0; c < 4; ++c) {
            xx[c] = eidx[s0 * N_EDGES + ee[c]];
            yy[c] = eidx[s1 * N_EDGES + ee[c]];
        }
#pragma unroll
        for (int c = 0; c < 4; ++c)
            at[c] = (bp + c < wp1) ? attbuf[(size_t)ee[c] * 4 + h] : 0.f;
        uint2 ua[4], ub[4];
#pragma unroll
        for (int c = 0; c < 4; ++c) {
            ua[c] = *(const uint2*)(tabs + (((size_t)xx[c] * 4 + h) * 5 + 3) * 64 + r * 4);
            ub[c] = *(const uint2*)(tabs + (((size_t)yy[c] * 4 + h) * 5 + 4) * 64 + r * 4);
        }
#pragma unroll
        for (int c = 0; c < 4; ++c) {
            const int p = bp + c;
            const int nl = (p >= o1) + (p >= o2) + (p >= o3);  // wave-uniform
            float g0 = __uint_as_float(ua[c].x << 16) + __uint_as_float(ub[c].x << 16);
            float g1 = __uint_as_float(ua[c].x & 0xffff0000u) + __uint_as_float(ub[c].x & 0xffff0000u);
            float g2 = __uint_as_float(ua[c].y << 16) + __uint_as_float(ub[c].y << 16);
            float g3 = __uint_as_float(ua[c].y & 0xffff0000u) + __uint_as_float(ub[c].y & 0xffff0000u);
            g0 = fmaxf(g0, 0.2f * g0); g1 = fmaxf(g1, 0.2f * g1);
            g2 = fmaxf(g2, 0.2f * g2); g3 = fmaxf(g3, 0.2f * g3);
            const float a = at[c];
            if (nl == 0) {
                c00 = fmaf(a, g0, c00); c01 = fmaf(a, g1, c01);
                c02 = fmaf(a, g2, c02); c03 = fmaf(a, g3, c03); al0 += a;
            } else if (nl == 1) {
                c10 = fmaf(a, g0, c10); c11 = fmaf(a, g1, c11);
                c12 = fmaf(a, g2, c12); c13 = fmaf(a, g3, c13); al1 += a;
            } else if (nl == 2) {
                c20 = fmaf(a, g0, c20); c21 = fmaf(a, g1, c21);
                c22 = fmaf(a, g2, c22); c23 = fmaf(a, g3, c23); al2 += a;
            } else {
                c30 = fmaf(a, g0, c30); c31 = fmaf(a, g1, c31);
                c32 = fmaf(a, g2, c32); c33 = fmaf(a, g3, c33); al3 += a;
            }
        }
    }
    {
        f32x4 v0 = {c00, c01, c02, c03};
        f32x4 v1 = {c10, c11, c12, c13};
        f32x4 v2 = {c20, c21, c22, c23};
        f32x4 v3 = {c30, c31, c32, c33};
        *(f32x4*)&part[w][h][r * 4]      = v0;
        *(f32x4*)&part[w][4 + h][r * 4]  = v1;
        *(f32x4*)&part[w][8 + h][r * 4]  = v2;
        *(f32x4*)&part[w][12 + h][r * 4] = v3;
        if (r == 0) {
            apart[w][h] = al0; apart[w][4 + h] = al1;
            apart[w][8 + h] = al2; apart[w][12 + h] = al3;
        }
    }
    __syncthreads();

    // ---- phase 1b: reduce 4 wave-partials -> bf16 A-tile ----
    {
        const int row = threadIdx.x >> 4;
        const int c4 = (threadIdx.x & 15) * 4;
        f32x4 s = *(f32x4*)&part[0][row][c4];
#pragma unroll
        for (int ww = 1; ww < 4; ++ww) {
            f32x4 pv = *(f32x4*)&part[ww][row][c4];
            s.x += pv.x; s.y += pv.y; s.z += pv.z; s.w += pv.w;
        }
        uint2 st;
        st.x = pack2(s.x, s.y);
        st.y = pack2(s.z, s.w);
        *(uint2*)&S_lds[row][c4] = st;
        if (threadIdx.x < 16)
            a_lds[threadIdx.x] = apart[0][threadIdx.x] + apart[1][threadIdx.x] +
                                 apart[2][threadIdx.x] + apart[3][threadIdx.x];
    }
    __syncthreads();

    // ---- phase 2: wave w = output-feature block ct; D[i][f] to LDS ----
    {
        const float* wp0p = eW2 + (w * 16 + r) * FD + q * 8;
        const float* wp1p = eW2 + (w * 16 + r) * FD + 32 + q * 8;
        short8 bfr0 = pack8(*(const float4*)wp0p, *(const float4*)(wp0p + 4));
        short8 bfr1 = pack8(*(const float4*)wp1p, *(const float4*)(wp1p + 4));
        short8 A0 = *(short8*)&S_lds[r][q * 8];
        short8 A1 = *(short8*)&S_lds[r][32 + q * 8];
        f32x4 acc = {0.f, 0.f, 0.f, 0.f};
        acc = __builtin_amdgcn_mfma_f32_16x16x32_bf16(A0, bfr0, acc, 0, 0, 0);
        acc = __builtin_amdgcn_mfma_f32_16x16x32_bf16(A1, bfr1, acc, 0, 0, 0);
#pragma unroll
        for (int i = 0; i < 4; ++i)
            D_lds[q * 4 + i][w * 16 + r] = acc[i];
    }
    __syncthreads();

    // ---- phase 3: cooperative vectorized epilogue ----
    const int row = threadIdx.x >> 4;          // 0..15 tile row
    const int c4 = threadIdx.x & 15;           // f-chunk of 4
    const int f = c4 * 4;
    const int hh = row & 3;
    const int nn = n0 + (row >> 2);
    const size_t rho = ((size_t)t * N_NODES + nn) * 4 + hh;

    float4 Dv = *(float4*)&D_lds[row][f];
    float4 pj = *(const float4*)(proj + (size_t)nn * HF + hh * 64 + f);
    float4 th = *(const float4*)(theta + hh * 64 + f);
    float4 bi = *(const float4*)(bias + hh * 64 + f);
    float4 b2 = *(const float4*)(eb2 + f);
    const float al = a_lds[row];
    float4 o;
    float v;
    v = th.x * pj.x + Dv.x + al * b2.x + bi.x; o.x = v > 0.f ? v : expm1f(v);
    v = th.y * pj.y + Dv.y + al * b2.y + bi.y; o.y = v > 0.f ? v : expm1f(v);
    v = th.z * pj.z + Dv.z + al * b2.z + bi.z; o.z = v > 0.f ? v : expm1f(v);
    v = th.w * pj.w + Dv.w + al * b2.w + bi.w; o.w = v > 0.f ? v : expm1f(v);
    *(float4*)(out + rho * 64 + f) = o;
}

// ---------------------------------------------------------------------------
extern "C" void kernel_launch(void* const* d_in, const int* in_sizes, int n_in,
                              void* d_out, int out_size, void* d_ws, size_t ws_size,
                              hipStream_t stream) {
    const float* in_nodes = (const float*)d_in[0];
    const int*   eidx     = (const int*)d_in[1];
    const float* Wp       = (const float*)d_in[2];
    const float* attW1    = (const float*)d_in[3];
    const float* attb1    = (const float*)d_in[4];
    const float* attW2    = (const float*)d_in[5];
    const float* attb2    = (const float*)d_in[6];
    const float* eW1      = (const float*)d_in[7];
    const float* eb1      = (const float*)d_in[8];
    const float* eW2      = (const float*)d_in[9];
    const float* eb2      = (const float*)d_in[10];
    const float* theta    = (const float*)d_in[11];
    const float* bias     = (const float*)d_in[12];

    char* ws = (char*)d_ws;
    float*          proj     = (float*)(ws + OFF_PROJ);
    __hip_bfloat16* tabs     = (__hip_bfloat16*)(ws + OFF_TABS);
    float*          attbuf   = (float*)(ws + OFF_ATT);
    int*            rank     = (int*)(ws + OFF_RANK);
    int*            elist    = (int*)(ws + OFF_ELIST);
    int*            cnt      = (int*)(ws + OFF_CNT);
    int*            offs     = (int*)(ws + OFF_OFFS);
    int*            bsums    = (int*)(ws + OFF_BSUM);
    __hip_bfloat16* Bsw      = (__hip_bfloat16*)(ws + OFF_BSW);
    float*          colbias  = (float*)(ws + OFF_CB);

    float* out = (float*)d_out;

    (void)hipMemsetAsync(cnt, 0, NT3 * sizeof(int), stream);

    k_comp<<<NCOLS, 128, 0, stream>>>(Wp, attW1, eW1, attb1, eb1, Bsw, colbias);
    k_tab<<<N_NODES / 16, 256, 0, stream>>>(in_nodes, Bsw, colbias, proj, tabs);

    k_hist<<<(E3 + 255) / 256, 256, 0, stream>>>(eidx, cnt, rank);
    k_scan1<<<(NT3 + 1023) / 1024, 256, 0, stream>>>(cnt, offs, bsums);
    k_scan2<<<1, 256, 0, stream>>>(bsums, (NT3 + 1023) / 1024);
    k_scan3<<<(NT3 + 256) / 256, 256, 0, stream>>>(offs, bsums);
    k_scat<<<(E3 + 255) / 256, 256, 0, stream>>>(eidx, offs, rank, elist);

    k_att<<<N_EDGES / 16, 256, 0, stream>>>(eidx, tabs, attW2, attb2, attbuf);
    k_seg<<<dim3(N_NODES / 4, 3), 256, 0, stream>>>(eidx, offs, elist, attbuf,
                                                    tabs, proj, eW2, eb2,
                                                    theta, bias, out);
}

// Round 11
// 366.575 us; speedup vs baseline: 1.1377x; 1.0643x over previous
//
#include <hip/hip_runtime.h>
#include <hip/hip_bf16.h>

#define N_NODES 50000
#define N_EDGES 200000
#define IN_F 128
#define HEADS 4
#define FD 64
#define HF 256
#define NCOLS 1536
#define NT3 (3 * N_NODES)          // 150000 segment rows (t-major)
#define E3  (3 * N_EDGES)          // 600000 slots
#define TROW 320                   // 5*64 bf16 per (node,head)

// ---- ws byte offsets ----
#define OFF_PROJ   0UL
#define OFF_TABS   51200000UL
#define OFF_ATT    179200000UL
#define OFF_RANK   182400000UL
#define OFF_ELIST2 184800000UL     // int4 per slot: (x, y, e, 0) — 9.6 MB
#define OFF_CNT    194400000UL
#define OFF_OFFS   195000000UL
#define OFF_BSUM   195600008UL
#define OFF_BSW    195601040UL
#define OFF_CB     195994256UL

typedef __attribute__((ext_vector_type(8))) short short8;
typedef __attribute__((ext_vector_type(4))) float f32x4;

__device__ inline short bf16_of(float x) {
    __hip_bfloat16 h = __float2bfloat16(x);
    return *reinterpret_cast<short*>(&h);
}
__device__ inline unsigned pack2(float lo, float hi) {
    return ((unsigned)(unsigned short)bf16_of(hi) << 16) |
           (unsigned)(unsigned short)bf16_of(lo);
}
__device__ inline short8 pack8(float4 a, float4 b) {
    short8 o;
    o[0] = bf16_of(a.x); o[1] = bf16_of(a.y); o[2] = bf16_of(a.z); o[3] = bf16_of(a.w);
    o[4] = bf16_of(b.x); o[5] = bf16_of(b.y); o[6] = bf16_of(b.z); o[7] = bf16_of(b.w);
    return o;
}
__device__ inline void unpk(uint4 v, float* f) {
    f[0] = __uint_as_float(v.x << 16); f[1] = __uint_as_float(v.x & 0xffff0000u);
    f[2] = __uint_as_float(v.y << 16); f[3] = __uint_as_float(v.y & 0xffff0000u);
    f[4] = __uint_as_float(v.z << 16); f[5] = __uint_as_float(v.z & 0xffff0000u);
    f[6] = __uint_as_float(v.w << 16); f[7] = __uint_as_float(v.w & 0xffff0000u);
}
__device__ inline float score8(uint4 ua, uint4 ub, uint4 uc, const float* w) {
    float fa[8], fb[8], fc[8]; unpk(ua, fa); unpk(ub, fb); unpk(uc, fc);
    float p = 0.f;
#pragma unroll
    for (int j = 0; j < 8; ++j) {
        float x = fa[j] + fb[j] + fc[j];
        x = fmaxf(x, 0.f);
        p = fmaf(x, w[j], p);
    }
    return p;
}

// ---------------------------------------------------------------------------
// K0: compose weights (table_W1 · W_proj_head) -> pre-swizzled B-frags + colbias
// ---------------------------------------------------------------------------
__global__ __launch_bounds__(128) void k_comp(const float* __restrict__ Wp,
                                              const float* __restrict__ attW1,
                                              const float* __restrict__ eW1,
                                              const float* __restrict__ attb1,
                                              const float* __restrict__ eb1,
                                              __hip_bfloat16* __restrict__ Bsw,
                                              float* __restrict__ colbias) {
    const int c = blockIdx.x;
    const int k = threadIdx.x;
    float acc;
    float cb = 0.f;
    if (c < HF) {
        acc = Wp[c * IN_F + k];
    } else {
        const int t = (c - HF) >> 8;
        const int rem = (c - HF) & 255;
        const int h = rem >> 6, g = rem & 63;
        const float* T;
        if (t == 0)      T = attW1 + g * 192;
        else if (t == 1) T = attW1 + g * 192 + 64;
        else if (t == 2) T = attW1 + g * 192 + 128;
        else if (t == 3) T = eW1 + g * 128;
        else             T = eW1 + g * 128 + 64;
        acc = 0.f;
        for (int f = 0; f < 64; ++f)
            acc += T[f] * Wp[(h * 64 + f) * IN_F + k];
        if (t == 0) cb = attb1[g];
        else if (t == 3) cb = eb1[g];
    }
    const int ct = c >> 4, cin = c & 15, kin = k & 31, j = k & 7;
    const int ks = k >> 5;
    const int l = cin + ((kin >> 3) << 4);
    Bsw[((ct * 4 + ks) * 64 + l) * 8 + j] = __float2bfloat16(acc);
    if (k == 0) colbias[c] = cb;
}

// ---------------------------------------------------------------------------
// K1: [50000x128] @ [128x1536] MFMA GEMM -> proj f32 + packed bf16 tables
// tabs layout: ((node*4 + h)*5 + t)*64 + g
// ---------------------------------------------------------------------------
__global__ __launch_bounds__(256) void k_tab(const float* __restrict__ in,
                                             const __hip_bfloat16* __restrict__ BswH,
                                             const float* __restrict__ colbias,
                                             float* __restrict__ proj,
                                             __hip_bfloat16* __restrict__ tabs) {
    const short8* Bsw = reinterpret_cast<const short8*>(BswH);
    const int lane = threadIdx.x & 63;
    const int wv = threadIdx.x >> 6;
    const int r = lane & 15, q = lane >> 4;
    const int row0 = blockIdx.x * 16;

    short8 a[4];
    const float* ip = in + (size_t)(row0 + r) * IN_F + q * 8;
#pragma unroll
    for (int ks = 0; ks < 4; ++ks)
        a[ks] = pack8(*(const float4*)(ip + ks * 32), *(const float4*)(ip + ks * 32 + 4));

    for (int ctl = 0; ctl < 24; ++ctl) {
        const int ct = wv * 24 + ctl;
        const int c = ct * 16 + r;
        const float cb = colbias[c];
        f32x4 acc = {cb, cb, cb, cb};
#pragma unroll
        for (int ks = 0; ks < 4; ++ks)
            acc = __builtin_amdgcn_mfma_f32_16x16x32_bf16(a[ks], Bsw[(ct * 4 + ks) * 64 + lane], acc, 0, 0, 0);
        if (c < HF) {
#pragma unroll
            for (int i = 0; i < 4; ++i)
                proj[(size_t)(row0 + q * 4 + i) * HF + c] = acc[i];
        } else {
            const int t = (c - HF) >> 8;
            const int rem = (c - HF) & 255;
            const int h = rem >> 6, g = rem & 63;
#pragma unroll
            for (int i = 0; i < 4; ++i)
                tabs[(((size_t)(row0 + q * 4 + i) * HEADS + h) * 5 + t) * 64 + g] =
                    __float2bfloat16(acc[i]);
        }
    }
}

// ---------------------------------------------------------------------------
// Sort chain: hist -> scan (3 kernels) -> scatter (x, y, e) triples
// ---------------------------------------------------------------------------
__global__ __launch_bounds__(256) void k_hist(const int* __restrict__ eidx,
                                              int* __restrict__ cnt,
                                              int* __restrict__ rank) {
    const int g = blockIdx.x * 256 + threadIdx.x;
    if (g < E3) {
        const int node = eidx[g];
        const int t = g / N_EDGES;
        rank[g] = atomicAdd(&cnt[t * N_NODES + node], 1);
    }
}

__global__ __launch_bounds__(256) void k_scan1(const int* __restrict__ cnt,
                                               int* __restrict__ offs,
                                               int* __restrict__ bsums) {
    __shared__ int lds[256];
    const int b = blockIdx.x, t = threadIdx.x;
    const int base = b * 1024 + t * 4;
    int v[4];
#pragma unroll
    for (int c = 0; c < 4; ++c) v[c] = (base + c < NT3) ? cnt[base + c] : 0;
    const int s = v[0] + v[1] + v[2] + v[3];
    lds[t] = s;
    __syncthreads();
    for (int off = 1; off < 256; off <<= 1) {
        int x = (t >= off) ? lds[t - off] : 0;
        __syncthreads();
        lds[t] += x;
        __syncthreads();
    }
    if (t == 255) bsums[b] = lds[255];
    int run = lds[t] - s;
#pragma unroll
    for (int c = 0; c < 4; ++c) {
        if (base + c < NT3) offs[base + c] = run;
        run += v[c];
    }
}

__global__ __launch_bounds__(256) void k_scan2(int* __restrict__ bsums, int nb) {
    __shared__ int lds[256];
    const int t = threadIdx.x;
    const int v = (t < nb) ? bsums[t] : 0;
    lds[t] = v;
    __syncthreads();
    for (int off = 1; off < 256; off <<= 1) {
        int x = (t >= off) ? lds[t - off] : 0;
        __syncthreads();
        lds[t] += x;
        __syncthreads();
    }
    if (t < nb) bsums[t] = lds[t] - v;
}

__global__ __launch_bounds__(256) void k_scan3(int* __restrict__ offs,
                                               const int* __restrict__ bsums) {
    const int i = blockIdx.x * 256 + threadIdx.x;
    if (i < NT3) offs[i] += bsums[i >> 10];
    if (i == NT3) offs[NT3] = E3;
}

__global__ __launch_bounds__(256) void k_scat(const int* __restrict__ eidx,
                                              const int* __restrict__ offs,
                                              const int* __restrict__ rank,
                                              int4* __restrict__ elist2) {
    const int g = blockIdx.x * 256 + threadIdx.x;
    if (g < E3) {
        const int node = eidx[g];
        const int t = g / N_EDGES;
        const int e = g - t * N_EDGES;
        const int s0 = (t == 0) ? 1 : 0;
        const int s1 = (t == 2) ? 1 : 2;
        const int x = eidx[s0 * N_EDGES + e];      // coalesced (e sequential)
        const int y = eidx[s1 * N_EDGES + e];
        elist2[offs[t * N_NODES + node] + rank[g]] = make_int4(x, y, e, 0);
    }
}

// ---------------------------------------------------------------------------
// K2: attention scores -> attbuf[e][4]. Block = 16 edges x 4 waves (wave=head).
// ---------------------------------------------------------------------------
__global__ __launch_bounds__(256) void k_att(
        const int* __restrict__ eidx,
        const __hip_bfloat16* __restrict__ tabs,
        const float* __restrict__ attW2, const float* __restrict__ attb2,
        float* __restrict__ attbuf) {
    __shared__ float s_lds[HEADS][16];
    const int lane = threadIdx.x & 63;
    const int h = threadIdx.x >> 6;
    const int r = lane & 15, q = lane >> 4;
    const int e0 = blockIdx.x * 16;

    float awlo[8], awhi[8];
    {
        float4 w0 = *(const float4*)(attW2 + q * 8);
        float4 w1 = *(const float4*)(attW2 + q * 8 + 4);
        awlo[0] = w0.x; awlo[1] = w0.y; awlo[2] = w0.z; awlo[3] = w0.w;
        awlo[4] = w1.x; awlo[5] = w1.y; awlo[6] = w1.z; awlo[7] = w1.w;
        float4 w2 = *(const float4*)(attW2 + 32 + q * 8);
        float4 w3 = *(const float4*)(attW2 + 32 + q * 8 + 4);
        awhi[0] = w2.x; awhi[1] = w2.y; awhi[2] = w2.z; awhi[3] = w2.w;
        awhi[4] = w3.x; awhi[5] = w3.y; awhi[6] = w3.z; awhi[7] = w3.w;
    }
    const float ab2s = attb2[0];

    const int ni = eidx[e0 + r];
    const int nj = eidx[N_EDGES + e0 + r];
    const int nk = eidx[2 * N_EDGES + e0 + r];

    const size_t bi = ((size_t)ni * HEADS + h) * TROW + q * 8;
    const size_t bj = ((size_t)nj * HEADS + h) * TROW + q * 8;
    const size_t bk = ((size_t)nk * HEADS + h) * TROW + q * 8;

    uint4 a0 = *(const uint4*)(tabs + bi);
    uint4 a1 = *(const uint4*)(tabs + bi + 32);
    uint4 b0 = *(const uint4*)(tabs + bj + 64);
    uint4 b1 = *(const uint4*)(tabs + bj + 96);
    uint4 c0 = *(const uint4*)(tabs + bk + 128);
    uint4 c1 = *(const uint4*)(tabs + bk + 160);

    float p = score8(a0, b0, c0, awlo) + score8(a1, b1, c1, awhi);
    p += __shfl_xor(p, 16);
    p += __shfl_xor(p, 32);
    float sc = p + ab2s;
    sc = fmaxf(sc, 0.2f * sc);
    if (lane < 16) s_lds[h][lane] = sc;
    __syncthreads();
    if (lane < 16) {
        const float s0 = s_lds[0][lane], s1 = s_lds[1][lane];
        const float s2 = s_lds[2][lane], s3 = s_lds[3][lane];
        const float mx = fmaxf(fmaxf(s0, s1), fmaxf(s2, s3));
        const float x0 = __expf(s0 - mx), x1 = __expf(s1 - mx);
        const float x2 = __expf(s2 - mx), x3 = __expf(s3 - mx);
        const float rs = 1.f / (x0 + x1 + x2 + x3);
        const float xh = (h == 0) ? x0 : (h == 1) ? x1 : (h == 2) ? x2 : x3;
        attbuf[(size_t)(e0 + lane) * 4 + h] = xh * rs;
    }
}

// ---------------------------------------------------------------------------
// K3 (fused): segment-sum + W2 GEMM + elu epilogue (R7 structure).
// Phase 1 reads pre-joined (x,y,e) triples: 2-level dependence chain
// (elist2 -> table gather) and 16 VMEM/chunk instead of 24.
// ---------------------------------------------------------------------------
__global__ __launch_bounds__(256) void k_seg(const int* __restrict__ offs,
                                             const int4* __restrict__ elist2,
                                             const float* __restrict__ attbuf,
                                             const __hip_bfloat16* __restrict__ tabs,
                                             const float* __restrict__ proj,
                                             const float* __restrict__ eW2,
                                             const float* __restrict__ eb2,
                                             const float* __restrict__ theta,
                                             const float* __restrict__ bias,
                                             float* __restrict__ out) {
    __shared__ __hip_bfloat16 S_lds[16][72];   // padded: stride 144 B
    __shared__ float a_lds[16];
    __shared__ float D_lds[16][68];            // padded: stride 272 B

    const int lane = threadIdx.x & 63;
    const int w = threadIdx.x >> 6;
    const int h = lane >> 4, r = lane & 15;
    const int q = lane >> 4;                   // MFMA quad index (phase 2)
    const int t = blockIdx.y;
    const int n0 = blockIdx.x * 4;
    const int n = n0 + w;
    const int idx = t * N_NODES + n;
    const int p0 = offs[idx], p1 = offs[idx + 1];

    // loop-invariant element offsets within a (node,head) row
    const int c1 = h * TROW + 192 + r * 4;     // v1 (t=3)
    const int c2 = h * TROW + 256 + r * 4;     // v2 (t=4)

    // ---- phase 1: 4-wide batched segment accumulation ----
    float acc0 = 0.f, acc1 = 0.f, acc2 = 0.f, acc3 = 0.f, alpha = 0.f;
    for (int base = p0; base < p1; base += 4) {
        int4 exy[4];
#pragma unroll
        for (int c = 0; c < 4; ++c) {
            const int p = base + c;
            exy[c] = elist2[p < p1 ? p : p1 - 1];    // clamp: stays in-segment
        }
        float at[4];
#pragma unroll
        for (int c = 0; c < 4; ++c)
            at[c] = (base + c < p1) ? attbuf[(size_t)exy[c].z * 4 + h] : 0.f;
        uint2 ua[4], ub[4];
#pragma unroll
        for (int c = 0; c < 4; ++c) {
            ua[c] = *(const uint2*)(tabs + ((size_t)exy[c].x * 1280 + c1));
            ub[c] = *(const uint2*)(tabs + ((size_t)exy[c].y * 1280 + c2));
        }
#pragma unroll
        for (int c = 0; c < 4; ++c) {
            float g0 = __uint_as_float(ua[c].x << 16) + __uint_as_float(ub[c].x << 16);
            float g1 = __uint_as_float(ua[c].x & 0xffff0000u) + __uint_as_float(ub[c].x & 0xffff0000u);
            float g2 = __uint_as_float(ua[c].y << 16) + __uint_as_float(ub[c].y << 16);
            float g3 = __uint_as_float(ua[c].y & 0xffff0000u) + __uint_as_float(ub[c].y & 0xffff0000u);
            g0 = fmaxf(g0, 0.2f * g0); g1 = fmaxf(g1, 0.2f * g1);
            g2 = fmaxf(g2, 0.2f * g2); g3 = fmaxf(g3, 0.2f * g3);
            acc0 = fmaf(at[c], g0, acc0); acc1 = fmaf(at[c], g1, acc1);
            acc2 = fmaf(at[c], g2, acc2); acc3 = fmaf(at[c], g3, acc3);
            alpha += at[c];
        }
    }
    const int tr = w * 4 + h;                  // tile row
    uint2 st;
    st.x = pack2(acc0, acc1);
    st.y = pack2(acc2, acc3);
    *(uint2*)&S_lds[tr][r * 4] = st;
    if (r == 0) a_lds[tr] = alpha;
    __syncthreads();

    // ---- phase 2: wave w = output-feature block ct; D[i][f] to LDS ----
    {
        const float* wp0 = eW2 + (w * 16 + r) * FD + q * 8;
        const float* wp1 = eW2 + (w * 16 + r) * FD + 32 + q * 8;
        short8 bfr0 = pack8(*(const float4*)wp0, *(const float4*)(wp0 + 4));
        short8 bfr1 = pack8(*(const float4*)wp1, *(const float4*)(wp1 + 4));
        short8 A0 = *(short8*)&S_lds[r][q * 8];
        short8 A1 = *(short8*)&S_lds[r][32 + q * 8];
        f32x4 acc = {0.f, 0.f, 0.f, 0.f};
        acc = __builtin_amdgcn_mfma_f32_16x16x32_bf16(A0, bfr0, acc, 0, 0, 0);
        acc = __builtin_amdgcn_mfma_f32_16x16x32_bf16(A1, bfr1, acc, 0, 0, 0);
#pragma unroll
        for (int i = 0; i < 4; ++i)
            D_lds[q * 4 + i][w * 16 + r] = acc[i];
    }
    __syncthreads();

    // ---- phase 3: cooperative vectorized epilogue ----
    const int row = threadIdx.x >> 4;          // 0..15 tile row
    const int c4 = threadIdx.x & 15;           // f-chunk of 4
    const int f = c4 * 4;
    const int hh = row & 3;
    const int nn = n0 + (row >> 2);
    const size_t rho = ((size_t)t * N_NODES + nn) * 4 + hh;

    float4 Dv = *(float4*)&D_lds[row][f];
    float4 pj = *(const float4*)(proj + (size_t)nn * HF + hh * 64 + f);
    float4 th = *(const float4*)(theta + hh * 64 + f);
    float4 bi = *(const float4*)(bias + hh * 64 + f);
    float4 b2 = *(const float4*)(eb2 + f);
    const float al = a_lds[row];
    float4 o;
    float v;
    v = th.x * pj.x + Dv.x + al * b2.x + bi.x; o.x = v > 0.f ? v : expm1f(v);
    v = th.y * pj.y + Dv.y + al * b2.y + bi.y; o.y = v > 0.f ? v : expm1f(v);
    v = th.z * pj.z + Dv.z + al * b2.z + bi.z; o.z = v > 0.f ? v : expm1f(v);
    v = th.w * pj.w + Dv.w + al * b2.w + bi.w; o.w = v > 0.f ? v : expm1f(v);
    *(float4*)(out + rho * 64 + f) = o;
}

// ---------------------------------------------------------------------------
extern "C" void kernel_launch(void* const* d_in, const int* in_sizes, int n_in,
                              void* d_out, int out_size, void* d_ws, size_t ws_size,
                              hipStream_t stream) {
    const float* in_nodes = (const float*)d_in[0];
    const int*   eidx     = (const int*)d_in[1];
    const float* Wp       = (const float*)d_in[2];
    const float* attW1    = (const float*)d_in[3];
    const float* attb1    = (const float*)d_in[4];
    const float* attW2    = (const float*)d_in[5];
    const float* attb2    = (const float*)d_in[6];
    const float* eW1      = (const float*)d_in[7];
    const float* eb1      = (const float*)d_in[8];
    const float* eW2      = (const float*)d_in[9];
    const float* eb2      = (const float*)d_in[10];
    const float* theta    = (const float*)d_in[11];
    const float* bias     = (const float*)d_in[12];

    char* ws = (char*)d_ws;
    float*          proj     = (float*)(ws + OFF_PROJ);
    __hip_bfloat16* tabs     = (__hip_bfloat16*)(ws + OFF_TABS);
    float*          attbuf   = (float*)(ws + OFF_ATT);
    int*            rank     = (int*)(ws + OFF_RANK);
    int4*           elist2   = (int4*)(ws + OFF_ELIST2);
    int*            cnt      = (int*)(ws + OFF_CNT);
    int*            offs     = (int*)(ws + OFF_OFFS);
    int*            bsums    = (int*)(ws + OFF_BSUM);
    __hip_bfloat16* Bsw      = (__hip_bfloat16*)(ws + OFF_BSW);
    float*          colbias  = (float*)(ws + OFF_CB);

    float* out = (float*)d_out;

    (void)hipMemsetAsync(cnt, 0, NT3 * sizeof(int), stream);

    k_comp<<<NCOLS, 128, 0, stream>>>(Wp, attW1, eW1, attb1, eb1, Bsw, colbias);
    k_tab<<<N_NODES / 16, 256, 0, stream>>>(in_nodes, Bsw, colbias, proj, tabs);

    k_hist<<<(E3 + 255) / 256, 256, 0, stream>>>(eidx, cnt, rank);
    k_scan1<<<(NT3 + 1023) / 1024, 256, 0, stream>>>(cnt, offs, bsums);
    k_scan2<<<1, 256, 0, stream>>>(bsums, (NT3 + 1023) / 1024);
    k_scan3<<<(NT3 + 256) / 256, 256, 0, stream>>>(offs, bsums);
    k_scat<<<(E3 + 255) / 256, 256, 0, stream>>>(eidx, offs, rank, elist2);

    k_att<<<N_EDGES / 16, 256, 0, stream>>>(eidx, tabs, attW2, attb2, attbuf);
    k_seg<<<dim3(N_NODES / 4, 3), 256, 0, stream>>>(offs, elist2, attbuf,
                                                    tabs, proj, eW2, eb2,
                                                    theta, bias, out);
}

// Round 12
// 353.114 us; speedup vs baseline: 1.1810x; 1.0381x over previous
//
#include <hip/hip_runtime.h>
#include <hip/hip_bf16.h>

#define N_NODES 50000
#define N_EDGES 200000
#define IN_F 128
#define HEADS 4
#define FD 64
#define HF 256
#define NCOLS 1536
#define NT3 (3 * N_NODES)          // 150000 segment rows (t-major)
#define E3  (3 * N_EDGES)          // 600000 slots
#define TROW 320                   // 5*64 bf16 per (node,head)

// ---- ws byte offsets ----
#define OFF_PROJ   0UL
#define OFF_TABS   51200000UL
#define OFF_ATT    179200000UL
#define OFF_RANK   182400000UL
#define OFF_ELIST2 184800000UL     // int4 per slot: (x, y, e, 0) — 9.6 MB
#define OFF_CNT    194400000UL
#define OFF_OFFS   195000000UL
#define OFF_BSUM   195600008UL
#define OFF_BSW    195601040UL
#define OFF_CB     195994256UL

typedef __attribute__((ext_vector_type(8))) short short8;
typedef __attribute__((ext_vector_type(4))) float f32x4;

__device__ inline short bf16_of(float x) {
    __hip_bfloat16 h = __float2bfloat16(x);
    return *reinterpret_cast<short*>(&h);
}
__device__ inline unsigned pack2(float lo, float hi) {
    return ((unsigned)(unsigned short)bf16_of(hi) << 16) |
           (unsigned)(unsigned short)bf16_of(lo);
}
__device__ inline short8 pack8(float4 a, float4 b) {
    short8 o;
    o[0] = bf16_of(a.x); o[1] = bf16_of(a.y); o[2] = bf16_of(a.z); o[3] = bf16_of(a.w);
    o[4] = bf16_of(b.x); o[5] = bf16_of(b.y); o[6] = bf16_of(b.z); o[7] = bf16_of(b.w);
    return o;
}
__device__ inline void unpk(uint4 v, float* f) {
    f[0] = __uint_as_float(v.x << 16); f[1] = __uint_as_float(v.x & 0xffff0000u);
    f[2] = __uint_as_float(v.y << 16); f[3] = __uint_as_float(v.y & 0xffff0000u);
    f[4] = __uint_as_float(v.z << 16); f[5] = __uint_as_float(v.z & 0xffff0000u);
    f[6] = __uint_as_float(v.w << 16); f[7] = __uint_as_float(v.w & 0xffff0000u);
}
__device__ inline float score8(uint4 ua, uint4 ub, uint4 uc, const float* w) {
    float fa[8], fb[8], fc[8]; unpk(ua, fa); unpk(ub, fb); unpk(uc, fc);
    float p = 0.f;
#pragma unroll
    for (int j = 0; j < 8; ++j) {
        float x = fa[j] + fb[j] + fc[j];
        x = fmaxf(x, 0.f);
        p = fmaf(x, w[j], p);
    }
    return p;
}

// ---------------------------------------------------------------------------
// K0: compose weights (table_W1 · W_proj_head) -> pre-swizzled B-frags + colbias
// ---------------------------------------------------------------------------
__global__ __launch_bounds__(128) void k_comp(const float* __restrict__ Wp,
                                              const float* __restrict__ attW1,
                                              const float* __restrict__ eW1,
                                              const float* __restrict__ attb1,
                                              const float* __restrict__ eb1,
                                              __hip_bfloat16* __restrict__ Bsw,
                                              float* __restrict__ colbias) {
    const int c = blockIdx.x;
    const int k = threadIdx.x;
    float acc;
    float cb = 0.f;
    if (c < HF) {
        acc = Wp[c * IN_F + k];
    } else {
        const int t = (c - HF) >> 8;
        const int rem = (c - HF) & 255;
        const int h = rem >> 6, g = rem & 63;
        const float* T;
        if (t == 0)      T = attW1 + g * 192;
        else if (t == 1) T = attW1 + g * 192 + 64;
        else if (t == 2) T = attW1 + g * 192 + 128;
        else if (t == 3) T = eW1 + g * 128;
        else             T = eW1 + g * 128 + 64;
        acc = 0.f;
        for (int f = 0; f < 64; ++f)
            acc += T[f] * Wp[(h * 64 + f) * IN_F + k];
        if (t == 0) cb = attb1[g];
        else if (t == 3) cb = eb1[g];
    }
    const int ct = c >> 4, cin = c & 15, kin = k & 31, j = k & 7;
    const int ks = k >> 5;
    const int l = cin + ((kin >> 3) << 4);
    Bsw[((ct * 4 + ks) * 64 + l) * 8 + j] = __float2bfloat16(acc);
    if (k == 0) colbias[c] = cb;
}

// ---------------------------------------------------------------------------
// K1: [50000x128] @ [128x1536] MFMA GEMM -> proj f32 + packed bf16 tables.
// Table stores staged through a per-wave LDS 16x16 transpose -> uint2 stores.
// ---------------------------------------------------------------------------
__global__ __launch_bounds__(256) void k_tab(const float* __restrict__ in,
                                             const __hip_bfloat16* __restrict__ BswH,
                                             const float* __restrict__ colbias,
                                             float* __restrict__ proj,
                                             __hip_bfloat16* __restrict__ tabs) {
    __shared__ __hip_bfloat16 st_lds[4][16][20];   // per-wave staging tile
    const short8* Bsw = reinterpret_cast<const short8*>(BswH);
    const int lane = threadIdx.x & 63;
    const int wv = threadIdx.x >> 6;
    const int r = lane & 15, q = lane >> 4;
    const int row0 = blockIdx.x * 16;

    short8 a[4];
    const float* ip = in + (size_t)(row0 + r) * IN_F + q * 8;
#pragma unroll
    for (int ks = 0; ks < 4; ++ks)
        a[ks] = pack8(*(const float4*)(ip + ks * 32), *(const float4*)(ip + ks * 32 + 4));

    for (int ctl = 0; ctl < 24; ++ctl) {
        const int ct = wv * 24 + ctl;
        const int c = ct * 16 + r;
        const float cb = colbias[c];
        f32x4 acc = {cb, cb, cb, cb};
#pragma unroll
        for (int ks = 0; ks < 4; ++ks)
            acc = __builtin_amdgcn_mfma_f32_16x16x32_bf16(a[ks], Bsw[(ct * 4 + ks) * 64 + lane], acc, 0, 0, 0);
        if (c < HF) {
#pragma unroll
            for (int i = 0; i < 4; ++i)
                proj[(size_t)(row0 + q * 4 + i) * HF + c] = acc[i];
        } else {
            // stage 16x16 bf16 tile in LDS (same-wave RAW; compiler waits)
#pragma unroll
            for (int i = 0; i < 4; ++i)
                st_lds[wv][q * 4 + i][r] = __float2bfloat16(acc[i]);
            const int rem0 = ct * 16 - HF;         // tile-uniform
            const int t = rem0 >> 8;
            const int h = (rem0 >> 6) & 3;
            const int g0 = rem0 & 63;              // multiple of 16
            const int rowl = lane >> 2, ch = lane & 3;
            uint2 val = *(const uint2*)&st_lds[wv][rowl][ch * 4];
            *(uint2*)(tabs + ((size_t)(row0 + rowl) * 4 + h) * TROW +
                      t * 64 + g0 + ch * 4) = val;
        }
    }
}

// ---------------------------------------------------------------------------
// Sort chain: hist -> scan (3 kernels) -> scatter (x, y, e) triples
// ---------------------------------------------------------------------------
__global__ __launch_bounds__(256) void k_hist(const int* __restrict__ eidx,
                                              int* __restrict__ cnt,
                                              int* __restrict__ rank) {
    const int g = blockIdx.x * 256 + threadIdx.x;
    if (g < E3) {
        const int node = eidx[g];
        const int t = g / N_EDGES;
        rank[g] = atomicAdd(&cnt[t * N_NODES + node], 1);
    }
}

__global__ __launch_bounds__(256) void k_scan1(const int* __restrict__ cnt,
                                               int* __restrict__ offs,
                                               int* __restrict__ bsums) {
    __shared__ int lds[256];
    const int b = blockIdx.x, t = threadIdx.x;
    const int base = b * 1024 + t * 4;
    int v[4];
#pragma unroll
    for (int c = 0; c < 4; ++c) v[c] = (base + c < NT3) ? cnt[base + c] : 0;
    const int s = v[0] + v[1] + v[2] + v[3];
    lds[t] = s;
    __syncthreads();
    for (int off = 1; off < 256; off <<= 1) {
        int x = (t >= off) ? lds[t - off] : 0;
        __syncthreads();
        lds[t] += x;
        __syncthreads();
    }
    if (t == 255) bsums[b] = lds[255];
    int run = lds[t] - s;
#pragma unroll
    for (int c = 0; c < 4; ++c) {
        if (base + c < NT3) offs[base + c] = run;
        run += v[c];
    }
}

__global__ __launch_bounds__(256) void k_scan2(int* __restrict__ bsums, int nb) {
    __shared__ int lds[256];
    const int t = threadIdx.x;
    const int v = (t < nb) ? bsums[t] : 0;
    lds[t] = v;
    __syncthreads();
    for (int off = 1; off < 256; off <<= 1) {
        int x = (t >= off) ? lds[t - off] : 0;
        __syncthreads();
        lds[t] += x;
        __syncthreads();
    }
    if (t < nb) bsums[t] = lds[t] - v;
}

__global__ __launch_bounds__(256) void k_scan3(int* __restrict__ offs,
                                               const int* __restrict__ bsums) {
    const int i = blockIdx.x * 256 + threadIdx.x;
    if (i < NT3) offs[i] += bsums[i >> 10];
    if (i == NT3) offs[NT3] = E3;
}

__global__ __launch_bounds__(256) void k_scat(const int* __restrict__ eidx,
                                              const int* __restrict__ offs,
                                              const int* __restrict__ rank,
                                              int4* __restrict__ elist2) {
    const int g = blockIdx.x * 256 + threadIdx.x;
    if (g < E3) {
        const int node = eidx[g];
        const int t = g / N_EDGES;
        const int e = g - t * N_EDGES;
        const int s0 = (t == 0) ? 1 : 0;
        const int s1 = (t == 2) ? 1 : 2;
        const int x = eidx[s0 * N_EDGES + e];      // coalesced (e sequential)
        const int y = eidx[s1 * N_EDGES + e];
        elist2[offs[t * N_NODES + node] + rank[g]] = make_int4(x, y, e, 0);
    }
}

// ---------------------------------------------------------------------------
// K2: attention scores -> attbuf[e][4]. Block = 16 edges x 4 waves (wave=head).
// ---------------------------------------------------------------------------
__global__ __launch_bounds__(256) void k_att(
        const int* __restrict__ eidx,
        const __hip_bfloat16* __restrict__ tabs,
        const float* __restrict__ attW2, const float* __restrict__ attb2,
        float* __restrict__ attbuf) {
    __shared__ float s_lds[HEADS][16];
    const int lane = threadIdx.x & 63;
    const int h = threadIdx.x >> 6;
    const int r = lane & 15, q = lane >> 4;
    const int e0 = blockIdx.x * 16;

    float awlo[8], awhi[8];
    {
        float4 w0 = *(const float4*)(attW2 + q * 8);
        float4 w1 = *(const float4*)(attW2 + q * 8 + 4);
        awlo[0] = w0.x; awlo[1] = w0.y; awlo[2] = w0.z; awlo[3] = w0.w;
        awlo[4] = w1.x; awlo[5] = w1.y; awlo[6] = w1.z; awlo[7] = w1.w;
        float4 w2 = *(const float4*)(attW2 + 32 + q * 8);
        float4 w3 = *(const float4*)(attW2 + 32 + q * 8 + 4);
        awhi[0] = w2.x; awhi[1] = w2.y; awhi[2] = w2.z; awhi[3] = w2.w;
        awhi[4] = w3.x; awhi[5] = w3.y; awhi[6] = w3.z; awhi[7] = w3.w;
    }
    const float ab2s = attb2[0];

    const int ni = eidx[e0 + r];
    const int nj = eidx[N_EDGES + e0 + r];
    const int nk = eidx[2 * N_EDGES + e0 + r];

    const size_t bi = ((size_t)ni * HEADS + h) * TROW + q * 8;
    const size_t bj = ((size_t)nj * HEADS + h) * TROW + q * 8;
    const size_t bk = ((size_t)nk * HEADS + h) * TROW + q * 8;

    uint4 a0 = *(const uint4*)(tabs + bi);
    uint4 a1 = *(const uint4*)(tabs + bi + 32);
    uint4 b0 = *(const uint4*)(tabs + bj + 64);
    uint4 b1 = *(const uint4*)(tabs + bj + 96);
    uint4 c0 = *(const uint4*)(tabs + bk + 128);
    uint4 c1 = *(const uint4*)(tabs + bk + 160);

    float p = score8(a0, b0, c0, awlo) + score8(a1, b1, c1, awhi);
    p += __shfl_xor(p, 16);
    p += __shfl_xor(p, 32);
    float sc = p + ab2s;
    sc = fmaxf(sc, 0.2f * sc);
    if (lane < 16) s_lds[h][lane] = sc;
    __syncthreads();
    if (lane < 16) {
        const float s0 = s_lds[0][lane], s1 = s_lds[1][lane];
        const float s2 = s_lds[2][lane], s3 = s_lds[3][lane];
        const float mx = fmaxf(fmaxf(s0, s1), fmaxf(s2, s3));
        const float x0 = __expf(s0 - mx), x1 = __expf(s1 - mx);
        const float x2 = __expf(s2 - mx), x3 = __expf(s3 - mx);
        const float rs = 1.f / (x0 + x1 + x2 + x3);
        const float xh = (h == 0) ? x0 : (h == 1) ? x1 : (h == 2) ? x2 : x3;
        attbuf[(size_t)(e0 + lane) * 4 + h] = xh * rs;
    }
}

// ---------------------------------------------------------------------------
// K3 (fused): segment-sum + W2 GEMM + elu epilogue.
// Block = 8 nodes (one t) x 4 waves; wave w owns nodes n0+w AND n0+4+w,
// interleaving both segments' gathers per chunk -> 2x MLP, half fixed cost.
// ---------------------------------------------------------------------------
__global__ __launch_bounds__(256) void k_seg(const int* __restrict__ offs,
                                             const int4* __restrict__ elist2,
                                             const float* __restrict__ attbuf,
                                             const __hip_bfloat16* __restrict__ tabs,
                                             const float* __restrict__ proj,
                                             const float* __restrict__ eW2,
                                             const float* __restrict__ eb2,
                                             const float* __restrict__ theta,
                                             const float* __restrict__ bias,
                                             float* __restrict__ out) {
    __shared__ __hip_bfloat16 S_lds[2][16][72];
    __shared__ float a_lds[2][16];
    __shared__ float D_lds[2][16][68];

    const int lane = threadIdx.x & 63;
    const int w = threadIdx.x >> 6;
    const int h = lane >> 4, r = lane & 15;
    const int q = lane >> 4;                   // MFMA quad index (phase 2)
    const int t = blockIdx.y;
    const int n0 = blockIdx.x * 8;
    const int idxA = t * N_NODES + n0 + w;
    const int idxB = idxA + 4;
    const int pA0 = offs[idxA], pA1 = offs[idxA + 1];
    const int pB0 = offs[idxB], pB1 = offs[idxB + 1];

    const int c1 = h * TROW + 192 + r * 4;     // v1 (t=3)
    const int c2 = h * TROW + 256 + r * 4;     // v2 (t=4)

    // ---- phase 1: dual-segment 4-wide batched accumulation ----
    float aA0 = 0.f, aA1 = 0.f, aA2 = 0.f, aA3 = 0.f, alA = 0.f;
    float aB0 = 0.f, aB1 = 0.f, aB2 = 0.f, aB3 = 0.f, alB = 0.f;
    int baseA = pA0, baseB = pB0;
    while (baseA < pA1 || baseB < pB1) {
        int4 eA[4], eB[4];
#pragma unroll
        for (int c = 0; c < 4; ++c) {
            int pa = baseA + c;
            int ia = pa < pA1 ? pa : pA1 - 1; ia = ia < 0 ? 0 : ia;
            eA[c] = elist2[ia];
            int pb = baseB + c;
            int ib = pb < pB1 ? pb : pB1 - 1; ib = ib < 0 ? 0 : ib;
            eB[c] = elist2[ib];
        }
        float atA[4], atB[4];
#pragma unroll
        for (int c = 0; c < 4; ++c) {
            atA[c] = (baseA + c < pA1) ? attbuf[(size_t)eA[c].z * 4 + h] : 0.f;
            atB[c] = (baseB + c < pB1) ? attbuf[(size_t)eB[c].z * 4 + h] : 0.f;
        }
        uint2 uaA[4], ubA[4], uaB[4], ubB[4];
#pragma unroll
        for (int c = 0; c < 4; ++c) {
            uaA[c] = *(const uint2*)(tabs + ((size_t)eA[c].x * 1280 + c1));
            ubA[c] = *(const uint2*)(tabs + ((size_t)eA[c].y * 1280 + c2));
            uaB[c] = *(const uint2*)(tabs + ((size_t)eB[c].x * 1280 + c1));
            ubB[c] = *(const uint2*)(tabs + ((size_t)eB[c].y * 1280 + c2));
        }
#pragma unroll
        for (int c = 0; c < 4; ++c) {
            float g0 = __uint_as_float(uaA[c].x << 16) + __uint_as_float(ubA[c].x << 16);
            float g1 = __uint_as_float(uaA[c].x & 0xffff0000u) + __uint_as_float(ubA[c].x & 0xffff0000u);
            float g2 = __uint_as_float(uaA[c].y << 16) + __uint_as_float(ubA[c].y << 16);
            float g3 = __uint_as_float(uaA[c].y & 0xffff0000u) + __uint_as_float(ubA[c].y & 0xffff0000u);
            g0 = fmaxf(g0, 0.2f * g0); g1 = fmaxf(g1, 0.2f * g1);
            g2 = fmaxf(g2, 0.2f * g2); g3 = fmaxf(g3, 0.2f * g3);
            aA0 = fmaf(atA[c], g0, aA0); aA1 = fmaf(atA[c], g1, aA1);
            aA2 = fmaf(atA[c], g2, aA2); aA3 = fmaf(atA[c], g3, aA3);
            alA += atA[c];
        }
#pragma unroll
        for (int c = 0; c < 4; ++c) {
            float g0 = __uint_as_float(uaB[c].x << 16) + __uint_as_float(ubB[c].x << 16);
            float g1 = __uint_as_float(uaB[c].x & 0xffff0000u) + __uint_as_float(ubB[c].x & 0xffff0000u);
            float g2 = __uint_as_float(uaB[c].y << 16) + __uint_as_float(ubB[c].y << 16);
            float g3 = __uint_as_float(uaB[c].y & 0xffff0000u) + __uint_as_float(ubB[c].y & 0xffff0000u);
            g0 = fmaxf(g0, 0.2f * g0); g1 = fmaxf(g1, 0.2f * g1);
            g2 = fmaxf(g2, 0.2f * g2); g3 = fmaxf(g3, 0.2f * g3);
            aB0 = fmaf(atB[c], g0, aB0); aB1 = fmaf(atB[c], g1, aB1);
            aB2 = fmaf(atB[c], g2, aB2); aB3 = fmaf(atB[c], g3, aB3);
            alB += atB[c];
        }
        baseA += 4; baseB += 4;
    }
    const int tr = w * 4 + h;
    {
        uint2 st;
        st.x = pack2(aA0, aA1); st.y = pack2(aA2, aA3);
        *(uint2*)&S_lds[0][tr][r * 4] = st;
        st.x = pack2(aB0, aB1); st.y = pack2(aB2, aB3);
        *(uint2*)&S_lds[1][tr][r * 4] = st;
        if (r == 0) { a_lds[0][tr] = alA; a_lds[1][tr] = alB; }
    }
    __syncthreads();

    // ---- phase 2: wave w = output-feature block; both tiles ----
    {
        const float* wp0 = eW2 + (w * 16 + r) * FD + q * 8;
        const float* wp1 = eW2 + (w * 16 + r) * FD + 32 + q * 8;
        short8 bfr0 = pack8(*(const float4*)wp0, *(const float4*)(wp0 + 4));
        short8 bfr1 = pack8(*(const float4*)wp1, *(const float4*)(wp1 + 4));
#pragma unroll
        for (int k = 0; k < 2; ++k) {
            short8 A0 = *(short8*)&S_lds[k][r][q * 8];
            short8 A1 = *(short8*)&S_lds[k][r][32 + q * 8];
            f32x4 acc = {0.f, 0.f, 0.f, 0.f};
            acc = __builtin_amdgcn_mfma_f32_16x16x32_bf16(A0, bfr0, acc, 0, 0, 0);
            acc = __builtin_amdgcn_mfma_f32_16x16x32_bf16(A1, bfr1, acc, 0, 0, 0);
#pragma unroll
            for (int i = 0; i < 4; ++i)
                D_lds[k][q * 4 + i][w * 16 + r] = acc[i];
        }
    }
    __syncthreads();

    // ---- phase 3: cooperative vectorized epilogue, both tiles ----
    const int row = threadIdx.x >> 4;
    const int c4 = threadIdx.x & 15;
    const int f = c4 * 4;
    const int hh = row & 3;
    float4 th = *(const float4*)(theta + hh * 64 + f);
    float4 bi = *(const float4*)(bias + hh * 64 + f);
    float4 b2 = *(const float4*)(eb2 + f);
#pragma unroll
    for (int k = 0; k < 2; ++k) {
        const int nn = n0 + k * 4 + (row >> 2);
        const size_t rho = ((size_t)t * N_NODES + nn) * 4 + hh;
        float4 Dv = *(float4*)&D_lds[k][row][f];
        float4 pj = *(const float4*)(proj + (size_t)nn * HF + hh * 64 + f);
        const float al = a_lds[k][row];
        float4 o;
        float v;
        v = th.x * pj.x + Dv.x + al * b2.x + bi.x; o.x = v > 0.f ? v : expm1f(v);
        v = th.y * pj.y + Dv.y + al * b2.y + bi.y; o.y = v > 0.f ? v : expm1f(v);
        v = th.z * pj.z + Dv.z + al * b2.z + bi.z; o.z = v > 0.f ? v : expm1f(v);
        v = th.w * pj.w + Dv.w + al * b2.w + bi.w; o.w = v > 0.f ? v : expm1f(v);
        *(float4*)(out + rho * 64 + f) = o;
    }
}

// ---------------------------------------------------------------------------
extern "C" void kernel_launch(void* const* d_in, const int* in_sizes, int n_in,
                              void* d_out, int out_size, void* d_ws, size_t ws_size,
                              hipStream_t stream) {
    const float* in_nodes = (const float*)d_in[0];
    const int*   eidx     = (const int*)d_in[1];
    const float* Wp       = (const float*)d_in[2];
    const float* attW1    = (const float*)d_in[3];
    const float* attb1    = (const float*)d_in[4];
    const float* attW2    = (const float*)d_in[5];
    const float* attb2    = (const float*)d_in[6];
    const float* eW1      = (const float*)d_in[7];
    const float* eb1      = (const float*)d_in[8];
    const float* eW2      = (const float*)d_in[9];
    const float* eb2      = (const float*)d_in[10];
    const float* theta    = (const float*)d_in[11];
    const float* bias     = (const float*)d_in[12];

    char* ws = (char*)d_ws;
    float*          proj     = (float*)(ws + OFF_PROJ);
    __hip_bfloat16* tabs     = (__hip_bfloat16*)(ws + OFF_TABS);
    float*          attbuf   = (float*)(ws + OFF_ATT);
    int*            rank     = (int*)(ws + OFF_RANK);
    int4*           elist2   = (int4*)(ws + OFF_ELIST2);
    int*            cnt      = (int*)(ws + OFF_CNT);
    int*            offs     = (int*)(ws + OFF_OFFS);
    int*            bsums    = (int*)(ws + OFF_BSUM);
    __hip_bfloat16* Bsw      = (__hip_bfloat16*)(ws + OFF_BSW);
    float*          colbias  = (float*)(ws + OFF_CB);

    float* out = (float*)d_out;

    (void)hipMemsetAsync(cnt, 0, NT3 * sizeof(int), stream);

    k_comp<<<NCOLS, 128, 0, stream>>>(Wp, attW1, eW1, attb1, eb1, Bsw, colbias);
    k_tab<<<N_NODES / 16, 256, 0, stream>>>(in_nodes, Bsw, colbias, proj, tabs);

    k_hist<<<(E3 + 255) / 256, 256, 0, stream>>>(eidx, cnt, rank);
    k_scan1<<<(NT3 + 1023) / 1024, 256, 0, stream>>>(cnt, offs, bsums);
    k_scan2<<<1, 256, 0, stream>>>(bsums, (NT3 + 1023) / 1024);
    k_scan3<<<(NT3 + 256) / 256, 256, 0, stream>>>(offs, bsums);
    k_scat<<<(E3 + 255) / 256, 256, 0, stream>>>(eidx, offs, rank, elist2);

    k_att<<<N_EDGES / 16, 256, 0, stream>>>(eidx, tabs, attW2, attb2, attbuf);
    k_seg<<<dim3(N_NODES / 8, 3), 256, 0, stream>>>(offs, elist2, attbuf,
                                                    tabs, proj, eW2, eb2,
                                                    theta, bias, out);
}

// Round 13
// 348.875 us; speedup vs baseline: 1.1954x; 1.0122x over previous
//
#include <hip/hip_runtime.h>
#include <hip/hip_bf16.h>

#define N_NODES 50000
#define N_EDGES 200000
#define IN_F 128
#define HEADS 4
#define FD 64
#define HF 256
#define NCOLS 1536
#define NT3 (3 * N_NODES)          // 150000 segment rows (t-major)
#define E3  (3 * N_EDGES)          // 600000 slots
#define TROW 320                   // 5*64 bf16 per (node,head)

// ---- ws byte offsets ----
#define OFF_PROJ   0UL
#define OFF_TABS   51200000UL
#define OFF_ATT    179200000UL
#define OFF_RANK   182400000UL
#define OFF_ELIST2 184800000UL     // int4 per slot: (x, y, e, 0) — 9.6 MB
#define OFF_CNT    194400000UL
#define OFF_OFFS   195000000UL
#define OFF_BSUM   195600008UL
#define OFF_BSW    195601040UL
#define OFF_CB     195994256UL

typedef __attribute__((ext_vector_type(8))) short short8;
typedef __attribute__((ext_vector_type(4))) float f32x4;

__device__ inline short bf16_of(float x) {
    __hip_bfloat16 h = __float2bfloat16(x);
    return *reinterpret_cast<short*>(&h);
}
__device__ inline unsigned pack2(float lo, float hi) {
    return ((unsigned)(unsigned short)bf16_of(hi) << 16) |
           (unsigned)(unsigned short)bf16_of(lo);
}
__device__ inline short8 pack8(float4 a, float4 b) {
    short8 o;
    o[0] = bf16_of(a.x); o[1] = bf16_of(a.y); o[2] = bf16_of(a.z); o[3] = bf16_of(a.w);
    o[4] = bf16_of(b.x); o[5] = bf16_of(b.y); o[6] = bf16_of(b.z); o[7] = bf16_of(b.w);
    return o;
}
__device__ inline void unpk(uint4 v, float* f) {
    f[0] = __uint_as_float(v.x << 16); f[1] = __uint_as_float(v.x & 0xffff0000u);
    f[2] = __uint_as_float(v.y << 16); f[3] = __uint_as_float(v.y & 0xffff0000u);
    f[4] = __uint_as_float(v.z << 16); f[5] = __uint_as_float(v.z & 0xffff0000u);
    f[6] = __uint_as_float(v.w << 16); f[7] = __uint_as_float(v.w & 0xffff0000u);
}
__device__ inline float score8(uint4 ua, uint4 ub, uint4 uc, const float* w) {
    float fa[8], fb[8], fc[8]; unpk(ua, fa); unpk(ub, fb); unpk(uc, fc);
    float p = 0.f;
#pragma unroll
    for (int j = 0; j < 8; ++j) {
        float x = fa[j] + fb[j] + fc[j];
        x = fmaxf(x, 0.f);
        p = fmaf(x, w[j], p);
    }
    return p;
}

// ---------------------------------------------------------------------------
// K0: compose weights (table_W1 · W_proj_head) -> pre-swizzled B-frags + colbias
// ---------------------------------------------------------------------------
__global__ __launch_bounds__(128) void k_comp(const float* __restrict__ Wp,
                                              const float* __restrict__ attW1,
                                              const float* __restrict__ eW1,
                                              const float* __restrict__ attb1,
                                              const float* __restrict__ eb1,
                                              __hip_bfloat16* __restrict__ Bsw,
                                              float* __restrict__ colbias) {
    const int c = blockIdx.x;
    const int k = threadIdx.x;
    float acc;
    float cb = 0.f;
    if (c < HF) {
        acc = Wp[c * IN_F + k];
    } else {
        const int t = (c - HF) >> 8;
        const int rem = (c - HF) & 255;
        const int h = rem >> 6, g = rem & 63;
        const float* T;
        if (t == 0)      T = attW1 + g * 192;
        else if (t == 1) T = attW1 + g * 192 + 64;
        else if (t == 2) T = attW1 + g * 192 + 128;
        else if (t == 3) T = eW1 + g * 128;
        else             T = eW1 + g * 128 + 64;
        acc = 0.f;
        for (int f = 0; f < 64; ++f)
            acc += T[f] * Wp[(h * 64 + f) * IN_F + k];
        if (t == 0) cb = attb1[g];
        else if (t == 3) cb = eb1[g];
    }
    const int ct = c >> 4, cin = c & 15, kin = k & 31, j = k & 7;
    const int ks = k >> 5;
    const int l = cin + ((kin >> 3) << 4);
    Bsw[((ct * 4 + ks) * 64 + l) * 8 + j] = __float2bfloat16(acc);
    if (k == 0) colbias[c] = cb;
}

// ---------------------------------------------------------------------------
// K1: [50000x128] @ [128x1536] MFMA GEMM -> proj f32 + packed bf16 tables.
// Table stores staged through a per-wave LDS 16x16 transpose -> uint2 stores.
// ---------------------------------------------------------------------------
__global__ __launch_bounds__(256) void k_tab(const float* __restrict__ in,
                                             const __hip_bfloat16* __restrict__ BswH,
                                             const float* __restrict__ colbias,
                                             float* __restrict__ proj,
                                             __hip_bfloat16* __restrict__ tabs) {
    __shared__ __hip_bfloat16 st_lds[4][16][20];   // per-wave staging tile
    const short8* Bsw = reinterpret_cast<const short8*>(BswH);
    const int lane = threadIdx.x & 63;
    const int wv = threadIdx.x >> 6;
    const int r = lane & 15, q = lane >> 4;
    const int row0 = blockIdx.x * 16;

    short8 a[4];
    const float* ip = in + (size_t)(row0 + r) * IN_F + q * 8;
#pragma unroll
    for (int ks = 0; ks < 4; ++ks)
        a[ks] = pack8(*(const float4*)(ip + ks * 32), *(const float4*)(ip + ks * 32 + 4));

    for (int ctl = 0; ctl < 24; ++ctl) {
        const int ct = wv * 24 + ctl;
        const int c = ct * 16 + r;
        const float cb = colbias[c];
        f32x4 acc = {cb, cb, cb, cb};
#pragma unroll
        for (int ks = 0; ks < 4; ++ks)
            acc = __builtin_amdgcn_mfma_f32_16x16x32_bf16(a[ks], Bsw[(ct * 4 + ks) * 64 + lane], acc, 0, 0, 0);
        if (c < HF) {
#pragma unroll
            for (int i = 0; i < 4; ++i)
                proj[(size_t)(row0 + q * 4 + i) * HF + c] = acc[i];
        } else {
            // stage 16x16 bf16 tile in LDS (same-wave RAW; compiler waits)
#pragma unroll
            for (int i = 0; i < 4; ++i)
                st_lds[wv][q * 4 + i][r] = __float2bfloat16(acc[i]);
            const int rem0 = ct * 16 - HF;         // tile-uniform
            const int t = rem0 >> 8;
            const int h = (rem0 >> 6) & 3;
            const int g0 = rem0 & 63;              // multiple of 16
            const int rowl = lane >> 2, ch = lane & 3;
            uint2 val = *(const uint2*)&st_lds[wv][rowl][ch * 4];
            *(uint2*)(tabs + ((size_t)(row0 + rowl) * 4 + h) * TROW +
                      t * 64 + g0 + ch * 4) = val;
        }
    }
}

// ---------------------------------------------------------------------------
// Sort chain: hist -> scan (3 kernels) -> scatter (x, y, e) triples
// ---------------------------------------------------------------------------
__global__ __launch_bounds__(256) void k_hist(const int* __restrict__ eidx,
                                              int* __restrict__ cnt,
                                              int* __restrict__ rank) {
    const int g = blockIdx.x * 256 + threadIdx.x;
    if (g < E3) {
        const int node = eidx[g];
        const int t = g / N_EDGES;
        rank[g] = atomicAdd(&cnt[t * N_NODES + node], 1);
    }
}

__global__ __launch_bounds__(256) void k_scan1(const int* __restrict__ cnt,
                                               int* __restrict__ offs,
                                               int* __restrict__ bsums) {
    __shared__ int lds[256];
    const int b = blockIdx.x, t = threadIdx.x;
    const int base = b * 1024 + t * 4;
    int v[4];
#pragma unroll
    for (int c = 0; c < 4; ++c) v[c] = (base + c < NT3) ? cnt[base + c] : 0;
    const int s = v[0] + v[1] + v[2] + v[3];
    lds[t] = s;
    __syncthreads();
    for (int off = 1; off < 256; off <<= 1) {
        int x = (t >= off) ? lds[t - off] : 0;
        __syncthreads();
        lds[t] += x;
        __syncthreads();
    }
    if (t == 255) bsums[b] = lds[255];
    int run = lds[t] - s;
#pragma unroll
    for (int c = 0; c < 4; ++c) {
        if (base + c < NT3) offs[base + c] = run;
        run += v[c];
    }
}

__global__ __launch_bounds__(256) void k_scan2(int* __restrict__ bsums, int nb) {
    __shared__ int lds[256];
    const int t = threadIdx.x;
    const int v = (t < nb) ? bsums[t] : 0;
    lds[t] = v;
    __syncthreads();
    for (int off = 1; off < 256; off <<= 1) {
        int x = (t >= off) ? lds[t - off] : 0;
        __syncthreads();
        lds[t] += x;
        __syncthreads();
    }
    if (t < nb) bsums[t] = lds[t] - v;
}

__global__ __launch_bounds__(256) void k_scan3(int* __restrict__ offs,
                                               const int* __restrict__ bsums) {
    const int i = blockIdx.x * 256 + threadIdx.x;
    if (i < NT3) offs[i] += bsums[i >> 10];
    if (i == NT3) offs[NT3] = E3;
}

__global__ __launch_bounds__(256) void k_scat(const int* __restrict__ eidx,
                                              const int* __restrict__ offs,
                                              const int* __restrict__ rank,
                                              int4* __restrict__ elist2) {
    const int g = blockIdx.x * 256 + threadIdx.x;
    if (g < E3) {
        const int node = eidx[g];
        const int t = g / N_EDGES;
        const int e = g - t * N_EDGES;
        const int s0 = (t == 0) ? 1 : 0;
        const int s1 = (t == 2) ? 1 : 2;
        const int x = eidx[s0 * N_EDGES + e];      // coalesced (e sequential)
        const int y = eidx[s1 * N_EDGES + e];
        elist2[offs[t * N_NODES + node] + rank[g]] = make_int4(x, y, e, 0);
    }
}

// ---------------------------------------------------------------------------
// K2: attention scores -> attbuf[e][4]. Block = 16 edges x 4 waves (wave=head).
// ---------------------------------------------------------------------------
__global__ __launch_bounds__(256) void k_att(
        const int* __restrict__ eidx,
        const __hip_bfloat16* __restrict__ tabs,
        const float* __restrict__ attW2, const float* __restrict__ attb2,
        float* __restrict__ attbuf) {
    __shared__ float s_lds[HEADS][16];
    const int lane = threadIdx.x & 63;
    const int h = threadIdx.x >> 6;
    const int r = lane & 15, q = lane >> 4;
    const int e0 = blockIdx.x * 16;

    float awlo[8], awhi[8];
    {
        float4 w0 = *(const float4*)(attW2 + q * 8);
        float4 w1 = *(const float4*)(attW2 + q * 8 + 4);
        awlo[0] = w0.x; awlo[1] = w0.y; awlo[2] = w0.z; awlo[3] = w0.w;
        awlo[4] = w1.x; awlo[5] = w1.y; awlo[6] = w1.z; awlo[7] = w1.w;
        float4 w2 = *(const float4*)(attW2 + 32 + q * 8);
        float4 w3 = *(const float4*)(attW2 + 32 + q * 8 + 4);
        awhi[0] = w2.x; awhi[1] = w2.y; awhi[2] = w2.z; awhi[3] = w2.w;
        awhi[4] = w3.x; awhi[5] = w3.y; awhi[6] = w3.z; awhi[7] = w3.w;
    }
    const float ab2s = attb2[0];

    const int ni = eidx[e0 + r];
    const int nj = eidx[N_EDGES + e0 + r];
    const int nk = eidx[2 * N_EDGES + e0 + r];

    const size_t bi = ((size_t)ni * HEADS + h) * TROW + q * 8;
    const size_t bj = ((size_t)nj * HEADS + h) * TROW + q * 8;
    const size_t bk = ((size_t)nk * HEADS + h) * TROW + q * 8;

    uint4 a0 = *(const uint4*)(tabs + bi);
    uint4 a1 = *(const uint4*)(tabs + bi + 32);
    uint4 b0 = *(const uint4*)(tabs + bj + 64);
    uint4 b1 = *(const uint4*)(tabs + bj + 96);
    uint4 c0 = *(const uint4*)(tabs + bk + 128);
    uint4 c1 = *(const uint4*)(tabs + bk + 160);

    float p = score8(a0, b0, c0, awlo) + score8(a1, b1, c1, awhi);
    p += __shfl_xor(p, 16);
    p += __shfl_xor(p, 32);
    float sc = p + ab2s;
    sc = fmaxf(sc, 0.2f * sc);
    if (lane < 16) s_lds[h][lane] = sc;
    __syncthreads();
    if (lane < 16) {
        const float s0 = s_lds[0][lane], s1 = s_lds[1][lane];
        const float s2 = s_lds[2][lane], s3 = s_lds[3][lane];
        const float mx = fmaxf(fmaxf(s0, s1), fmaxf(s2, s3));
        const float x0 = __expf(s0 - mx), x1 = __expf(s1 - mx);
        const float x2 = __expf(s2 - mx), x3 = __expf(s3 - mx);
        const float rs = 1.f / (x0 + x1 + x2 + x3);
        const float xh = (h == 0) ? x0 : (h == 1) ? x1 : (h == 2) ? x2 : x3;
        attbuf[(size_t)(e0 + lane) * 4 + h] = xh * rs;
    }
}

// ---------------------------------------------------------------------------
// K3 (fused): segment-sum + W2 GEMM + elu epilogue.
// Block = 8 nodes (one t) x 4 waves; wave w owns nodes n0+w AND n0+4+w.
// Phase 1 slot descriptors are wave-uniform -> readfirstlane to SGPRs so all
// gather addressing runs on the scalar pipe (saddr-form loads, ~0 VALU).
// ---------------------------------------------------------------------------
__global__ __launch_bounds__(256) void k_seg(const int* __restrict__ offs,
                                             const int4* __restrict__ elist2,
                                             const float* __restrict__ attbuf,
                                             const __hip_bfloat16* __restrict__ tabs,
                                             const float* __restrict__ proj,
                                             const float* __restrict__ eW2,
                                             const float* __restrict__ eb2,
                                             const float* __restrict__ theta,
                                             const float* __restrict__ bias,
                                             float* __restrict__ out) {
    __shared__ __hip_bfloat16 S_lds[2][16][72];
    __shared__ float a_lds[2][16];
    __shared__ float D_lds[2][16][68];

    const int lane = threadIdx.x & 63;
    const int w = threadIdx.x >> 6;
    const int h = lane >> 4, r = lane & 15;
    const int q = lane >> 4;                   // MFMA quad index (phase 2)
    const int t = blockIdx.y;
    const int n0 = blockIdx.x * 8;
    const int idxA = t * N_NODES + n0 + w;
    const int idxB = idxA + 4;
    const int pA0 = offs[idxA], pA1 = offs[idxA + 1];
    const int pB0 = offs[idxB], pB1 = offs[idxB + 1];

    const int c1 = h * TROW + 192 + r * 4;     // v1 (t=3), lane offset
    const int c2 = h * TROW + 256 + r * 4;     // v2 (t=4), lane offset
    const int c_at = h;                        // attbuf lane offset

    // ---- phase 1: dual-segment 4-wide batched accumulation, scalar addr ----
    float aA0 = 0.f, aA1 = 0.f, aA2 = 0.f, aA3 = 0.f, alA = 0.f;
    float aB0 = 0.f, aB1 = 0.f, aB2 = 0.f, aB3 = 0.f, alB = 0.f;
    int baseA = pA0, baseB = pB0;
    while (baseA < pA1 || baseB < pB1) {
        // 1. issue all 8 slot-descriptor loads (uniform addr -> broadcast)
        int4 evA[4], evB[4];
#pragma unroll
        for (int c = 0; c < 4; ++c) {
            int pa = baseA + c;
            int ia = pa < pA1 ? pa : pA1 - 1; ia = ia < 0 ? 0 : ia;
            evA[c] = elist2[ia];
            int pb = baseB + c;
            int ib = pb < pB1 ? pb : pB1 - 1; ib = ib < 0 ? 0 : ib;
            evB[c] = elist2[ib];
        }
        // 2. hoist to SGPRs — all downstream addressing goes scalar
        int xA[4], yA[4], zA[4], xB[4], yB[4], zB[4];
#pragma unroll
        for (int c = 0; c < 4; ++c) {
            xA[c] = __builtin_amdgcn_readfirstlane(evA[c].x);
            yA[c] = __builtin_amdgcn_readfirstlane(evA[c].y);
            zA[c] = __builtin_amdgcn_readfirstlane(evA[c].z);
            xB[c] = __builtin_amdgcn_readfirstlane(evB[c].x);
            yB[c] = __builtin_amdgcn_readfirstlane(evB[c].y);
            zB[c] = __builtin_amdgcn_readfirstlane(evB[c].z);
        }
        // 3. issue all att + table gathers (SGPR base + lane offset)
        float atA[4], atB[4];
#pragma unroll
        for (int c = 0; c < 4; ++c) {
            atA[c] = (baseA + c < pA1) ? attbuf[(size_t)zA[c] * 4 + c_at] : 0.f;
            atB[c] = (baseB + c < pB1) ? attbuf[(size_t)zB[c] * 4 + c_at] : 0.f;
        }
        uint2 uaA[4], ubA[4], uaB[4], ubB[4];
#pragma unroll
        for (int c = 0; c < 4; ++c) {
            uaA[c] = *(const uint2*)(tabs + (size_t)xA[c] * 1280 + c1);
            ubA[c] = *(const uint2*)(tabs + (size_t)yA[c] * 1280 + c2);
            uaB[c] = *(const uint2*)(tabs + (size_t)xB[c] * 1280 + c1);
            ubB[c] = *(const uint2*)(tabs + (size_t)yB[c] * 1280 + c2);
        }
        // 4. math
#pragma unroll
        for (int c = 0; c < 4; ++c) {
            float g0 = __uint_as_float(uaA[c].x << 16) + __uint_as_float(ubA[c].x << 16);
            float g1 = __uint_as_float(uaA[c].x & 0xffff0000u) + __uint_as_float(ubA[c].x & 0xffff0000u);
            float g2 = __uint_as_float(uaA[c].y << 16) + __uint_as_float(ubA[c].y << 16);
            float g3 = __uint_as_float(uaA[c].y & 0xffff0000u) + __uint_as_float(ubA[c].y & 0xffff0000u);
            g0 = fmaxf(g0, 0.2f * g0); g1 = fmaxf(g1, 0.2f * g1);
            g2 = fmaxf(g2, 0.2f * g2); g3 = fmaxf(g3, 0.2f * g3);
            aA0 = fmaf(atA[c], g0, aA0); aA1 = fmaf(atA[c], g1, aA1);
            aA2 = fmaf(atA[c], g2, aA2); aA3 = fmaf(atA[c], g3, aA3);
            alA += atA[c];
        }
#pragma unroll
        for (int c = 0; c < 4; ++c) {
            float g0 = __uint_as_float(uaB[c].x << 16) + __uint_as_float(ubB[c].x << 16);
            float g1 = __uint_as_float(uaB[c].x & 0xffff0000u) + __uint_as_float(ubB[c].x & 0xffff0000u);
            float g2 = __uint_as_float(uaB[c].y << 16) + __uint_as_float(ubB[c].y << 16);
            float g3 = __uint_as_float(uaB[c].y & 0xffff0000u) + __uint_as_float(ubB[c].y & 0xffff0000u);
            g0 = fmaxf(g0, 0.2f * g0); g1 = fmaxf(g1, 0.2f * g1);
            g2 = fmaxf(g2, 0.2f * g2); g3 = fmaxf(g3, 0.2f * g3);
            aB0 = fmaf(atB[c], g0, aB0); aB1 = fmaf(atB[c], g1, aB1);
            aB2 = fmaf(atB[c], g2, aB2); aB3 = fmaf(atB[c], g3, aB3);
            alB += atB[c];
        }
        baseA += 4; baseB += 4;
    }
    const int tr = w * 4 + h;
    {
        uint2 st;
        st.x = pack2(aA0, aA1); st.y = pack2(aA2, aA3);
        *(uint2*)&S_lds[0][tr][r * 4] = st;
        st.x = pack2(aB0, aB1); st.y = pack2(aB2, aB3);
        *(uint2*)&S_lds[1][tr][r * 4] = st;
        if (r == 0) { a_lds[0][tr] = alA; a_lds[1][tr] = alB; }
    }
    __syncthreads();

    // ---- phase 2: wave w = output-feature block; both tiles ----
    {
        const float* wp0 = eW2 + (w * 16 + r) * FD + q * 8;
        const float* wp1 = eW2 + (w * 16 + r) * FD + 32 + q * 8;
        short8 bfr0 = pack8(*(const float4*)wp0, *(const float4*)(wp0 + 4));
        short8 bfr1 = pack8(*(const float4*)wp1, *(const float4*)(wp1 + 4));
#pragma unroll
        for (int k = 0; k < 2; ++k) {
            short8 A0 = *(short8*)&S_lds[k][r][q * 8];
            short8 A1 = *(short8*)&S_lds[k][r][32 + q * 8];
            f32x4 acc = {0.f, 0.f, 0.f, 0.f};
            acc = __builtin_amdgcn_mfma_f32_16x16x32_bf16(A0, bfr0, acc, 0, 0, 0);
            acc = __builtin_amdgcn_mfma_f32_16x16x32_bf16(A1, bfr1, acc, 0, 0, 0);
#pragma unroll
            for (int i = 0; i < 4; ++i)
                D_lds[k][q * 4 + i][w * 16 + r] = acc[i];
        }
    }
    __syncthreads();

    // ---- phase 3: cooperative vectorized epilogue, both tiles ----
    const int row = threadIdx.x >> 4;
    const int c4 = threadIdx.x & 15;
    const int f = c4 * 4;
    const int hh = row & 3;
    float4 th = *(const float4*)(theta + hh * 64 + f);
    float4 bi = *(const float4*)(bias + hh * 64 + f);
    float4 b2 = *(const float4*)(eb2 + f);
#pragma unroll
    for (int k = 0; k < 2; ++k) {
        const int nn = n0 + k * 4 + (row >> 2);
        const size_t rho = ((size_t)t * N_NODES + nn) * 4 + hh;
        float4 Dv = *(float4*)&D_lds[k][row][f];
        float4 pj = *(const float4*)(proj + (size_t)nn * HF + hh * 64 + f);
        const float al = a_lds[k][row];
        float4 o;
        float v;
        v = th.x * pj.x + Dv.x + al * b2.x + bi.x; o.x = v > 0.f ? v : expm1f(v);
        v = th.y * pj.y + Dv.y + al * b2.y + bi.y; o.y = v > 0.f ? v : expm1f(v);
        v = th.z * pj.z + Dv.z + al * b2.z + bi.z; o.z = v > 0.f ? v : expm1f(v);
        v = th.w * pj.w + Dv.w + al * b2.w + bi.w; o.w = v > 0.f ? v : expm1f(v);
        *(float4*)(out + rho * 64 + f) = o;
    }
}

// ---------------------------------------------------------------------------
extern "C" void kernel_launch(void* const* d_in, const int* in_sizes, int n_in,
                              void* d_out, int out_size, void* d_ws, size_t ws_size,
                              hipStream_t stream) {
    const float* in_nodes = (const float*)d_in[0];
    const int*   eidx     = (const int*)d_in[1];
    const float* Wp       = (const float*)d_in[2];
    const float* attW1    = (const float*)d_in[3];
    const float* attb1    = (const float*)d_in[4];
    const float* attW2    = (const float*)d_in[5];
    const float* attb2    = (const float*)d_in[6];
    const float* eW1      = (const float*)d_in[7];
    const float* eb1      = (const float*)d_in[8];
    const float* eW2      = (const float*)d_in[9];
    const float* eb2      = (const float*)d_in[10];
    const float* theta    = (const float*)d_in[11];
    const float* bias     = (const float*)d_in[12];

    char* ws = (char*)d_ws;
    float*          proj     = (float*)(ws + OFF_PROJ);
    __hip_bfloat16* tabs     = (__hip_bfloat16*)(ws + OFF_TABS);
    float*          attbuf   = (float*)(ws + OFF_ATT);
    int*            rank     = (int*)(ws + OFF_RANK);
    int4*           elist2   = (int4*)(ws + OFF_ELIST2);
    int*            cnt      = (int*)(ws + OFF_CNT);
    int*            offs     = (int*)(ws + OFF_OFFS);
    int*            bsums    = (int*)(ws + OFF_BSUM);
    __hip_bfloat16* Bsw      = (__hip_bfloat16*)(ws + OFF_BSW);
    float*          colbias  = (float*)(ws + OFF_CB);

    float* out = (float*)d_out;

    (void)hipMemsetAsync(cnt, 0, NT3 * sizeof(int), stream);

    k_comp<<<NCOLS, 128, 0, stream>>>(Wp, attW1, eW1, attb1, eb1, Bsw, colbias);
    k_tab<<<N_NODES / 16, 256, 0, stream>>>(in_nodes, Bsw, colbias, proj, tabs);

    k_hist<<<(E3 + 255) / 256, 256, 0, stream>>>(eidx, cnt, rank);
    k_scan1<<<(NT3 + 1023) / 1024, 256, 0, stream>>>(cnt, offs, bsums);
    k_scan2<<<1, 256, 0, stream>>>(bsums, (NT3 + 1023) / 1024);
    k_scan3<<<(NT3 + 256) / 256, 256, 0, stream>>>(offs, bsums);
    k_scat<<<(E3 + 255) / 256, 256, 0, stream>>>(eidx, offs, rank, elist2);

    k_att<<<N_EDGES / 16, 256, 0, stream>>>(eidx, tabs, attW2, attb2, attbuf);
    k_seg<<<dim3(N_NODES / 8, 3), 256, 0, stream>>>(offs, elist2, attbuf,
                                                    tabs, proj, eW2, eb2,
                                                    theta, bias, out);
}